// Round 3
// baseline (718.428 us; speedup 1.0000x reference)
//
#include <hip/hip_runtime.h>
#include <stdint.h>

#define B_DIM 4
#define S_DIM 2048
#define D_DIM 2048
#define H_DIM 16
#define M_ROWS (B_DIM * S_DIM)   // 8192
#define CONCAT_LD 4096
#define NCHUNK 32
#define CHLEN (S_DIM / NCHUNK)   // 64

#define BM 128
#define BN 128
#define BK 64

typedef __attribute__((ext_vector_type(8))) __bf16 bf16x8;
typedef __attribute__((ext_vector_type(4))) float f32x4;

__device__ inline unsigned short f2bf(float f) {
  union { float f; unsigned u; } x; x.f = f;
  unsigned r = x.u + 0x7fffu + ((x.u >> 16) & 1u);
  return (unsigned short)(r >> 16);
}
__device__ inline float bf2f(unsigned short s) {
  union { unsigned u; float f; } x; x.u = ((unsigned)s) << 16;
  return x.f;
}

// ---- fused: x fp32 -> bf16 into concat[:,0:2048]  AND  logits = x @ W_att ----
__global__ __launch_bounds__(256) void xconv_logits_kernel(
    const float* __restrict__ x, const float* __restrict__ Watt,
    unsigned short* __restrict__ concat, float* __restrict__ logits) {
  int row = blockIdx.x, t = threadIdx.x;
  const float* xr = x + (size_t)row * D_DIM;
  unsigned short* cr = concat + (size_t)row * CONCAT_LD;
  float p[H_DIM];
#pragma unroll
  for (int h = 0; h < H_DIM; ++h) p[h] = 0.f;
#pragma unroll
  for (int i = 0; i < 8; ++i) {
    int k = t + i * 256;
    float xv = xr[k];
    cr[k] = f2bf(xv);
    const float* wr = Watt + (size_t)k * H_DIM;
#pragma unroll
    for (int h = 0; h < H_DIM; ++h) p[h] += xv * wr[h];
  }
  __shared__ float red[4][H_DIM];
  int l = t & 63, w = t >> 6;
#pragma unroll
  for (int h = 0; h < H_DIM; ++h) {
    float v = p[h];
    for (int off = 32; off; off >>= 1) v += __shfl_down(v, off);
    if (l == 0) red[w][h] = v;
  }
  __syncthreads();
  if (t < H_DIM)
    logits[(size_t)row * H_DIM + t] = red[0][t] + red[1][t] + red[2][t] + red[3][t];
}

// ---- fp32 [R][C] -> bf16 transposed [C][R], dst leading dim ldd ----
__global__ __launch_bounds__(256) void transpose_conv_kernel(
    const float* __restrict__ src, unsigned short* __restrict__ dst,
    int R, int C, int ldd) {
  __shared__ float tile[32][33];
  int c0 = blockIdx.x * 32, r0 = blockIdx.y * 32;
  int tx = threadIdx.x & 31, ty = threadIdx.x >> 5;
#pragma unroll
  for (int i = 0; i < 32; i += 8)
    tile[ty + i][tx] = src[(size_t)(r0 + ty + i) * C + c0 + tx];
  __syncthreads();
#pragma unroll
  for (int i = 0; i < 32; i += 8)
    dst[(size_t)(c0 + ty + i) * ldd + r0 + tx] = f2bf(tile[tx][ty + i]);
}

// ---- fp32 -> bf16 plain convert (contiguous) ----
__global__ __launch_bounds__(256) void convert_kernel(
    const float* __restrict__ src, unsigned short* __restrict__ dst) {
  int idx = (blockIdx.x * 256 + threadIdx.x) * 4;
  const float4 v = *(const float4*)(src + idx);
  ushort4 o;
  o.x = f2bf(v.x); o.y = f2bf(v.y); o.z = f2bf(v.z); o.w = f2bf(v.w);
  *(ushort4*)(dst + idx) = o;
}

// ---- per (b,h): max over s, then coef = w/(w*(s+1)+1e-30), w=exp((lg-mx)*T) ----
__global__ __launch_bounds__(256) void coef_kernel(
    const float* __restrict__ logits, const float* __restrict__ temp, float* __restrict__ coef) {
  int b = blockIdx.x >> 4, h = blockIdx.x & 15;
  int t = threadIdx.x;
  const float* lg = logits + (size_t)b * S_DIM * H_DIM + h;
  float mx = -1e30f;
  for (int s = t; s < S_DIM; s += 256) mx = fmaxf(mx, lg[(size_t)s * H_DIM]);
  for (int off = 32; off; off >>= 1) mx = fmaxf(mx, __shfl_down(mx, off));
  __shared__ float red[4];
  if ((t & 63) == 0) red[t >> 6] = mx;
  __syncthreads();
  mx = fmaxf(fmaxf(red[0], red[1]), fmaxf(red[2], red[3]));
  float T = temp[h];
  float* cf = coef + (size_t)b * S_DIM * H_DIM + h;
  for (int s = t; s < S_DIM; s += 256) {
    float w = expf((lg[(size_t)s * H_DIM] - mx) * T);
    cf[(size_t)s * H_DIM] = w / (w * (float)(s + 1) + 1e-30f);
  }
}

// ---- bias2 = vector @ F1b (+ ff1_b), partial over j-segments then reduce ----
__global__ __launch_bounds__(256) void bias2_partial_kernel(
    const float* __restrict__ vector, const float* __restrict__ ff1,
    float* __restrict__ part) {
  int n = blockIdx.x * 256 + threadIdx.x;
  int seg = blockIdx.y, b = blockIdx.z;
  const float* vr = vector + (size_t)b * 2048 + seg * 128;
  const float* fr = ff1 + (size_t)(2048 + seg * 128) * 2048 + n;
  float acc = 0.f;
#pragma unroll 8
  for (int j = 0; j < 128; ++j) acc += vr[j] * fr[(size_t)j * 2048];
  part[((size_t)seg * 4 + b) * 2048 + n] = acc;
}

__global__ __launch_bounds__(256) void bias2_reduce_kernel(
    const float* __restrict__ part, const float* __restrict__ ff1_b,
    float* __restrict__ bias2) {
  int n = blockIdx.x * 256 + threadIdx.x;
  int b = blockIdx.y;
  float acc = ff1_b[n];
#pragma unroll
  for (int s = 0; s < 16; ++s) acc += part[((size_t)s * 4 + b) * 2048 + n];
  bias2[(size_t)b * 2048 + n] = acc;
}

// ---- 128x128 GEMM (m97 structure) -- kept for the small 2048^3 Wc GEMM ----
template <int MODE>
__global__ __launch_bounds__(256) void gemm_bt_kernel(
    const unsigned short* __restrict__ A, int lda,
    const unsigned short* __restrict__ Bt, int ldb, int K,
    void* __restrict__ outp, int ldo,
    const float* __restrict__ bias, const float* __restrict__ resid) {
  __shared__ unsigned short As[BM * BK];
  __shared__ unsigned short Bs[BN * BK];
  const int t = threadIdx.x;
  const int w = t >> 6, l = t & 63;
  const int wm = w & 1, wn = w >> 1;
  const int q = l >> 4, ln = l & 15;

  const int L = blockIdx.y * 16 + blockIdx.x;
  const int xcd = L & 7;
  const int W = L >> 3;
  const int bx = W & 15;
  const int by = (W >> 4) * 8 + xcd;
  const int m0 = by * BM, n0 = bx * BN;

  f32x4 acc[4][4];
#pragma unroll
  for (int i = 0; i < 4; ++i)
#pragma unroll
    for (int j = 0; j < 4; ++j) acc[i][j] = {0.f, 0.f, 0.f, 0.f};

  for (int k0 = 0; k0 < K; k0 += BK) {
    __syncthreads();
#pragma unroll
    for (int r = 0; r < 4; ++r) {
      int s = r * 256 + t;
      int row = s >> 3;
      int ch = (s & 7) ^ (row & 7);
      const unsigned short* ga = A + (size_t)(m0 + row) * lda + k0 + ch * 8;
      __builtin_amdgcn_global_load_lds(
          (const __attribute__((address_space(1))) void*)ga,
          (__attribute__((address_space(3))) void*)(As + (r * 256 + w * 64) * 8), 16, 0, 0);
      const unsigned short* gb = Bt + (size_t)(n0 + row) * ldb + k0 + ch * 8;
      __builtin_amdgcn_global_load_lds(
          (const __attribute__((address_space(1))) void*)gb,
          (__attribute__((address_space(3))) void*)(Bs + (r * 256 + w * 64) * 8), 16, 0, 0);
    }
    __syncthreads();
#pragma unroll
    for (int h = 0; h < 2; ++h) {
      bf16x8 af[4], bfr[4];
#pragma unroll
      for (int mt = 0; mt < 4; ++mt) {
        int ar = wm * 64 + mt * 16 + ln;
        af[mt] = *(const bf16x8*)&As[ar * BK + (((h * 4 + q) ^ (ar & 7)) * 8)];
      }
#pragma unroll
      for (int nt = 0; nt < 4; ++nt) {
        int br = wn * 64 + nt * 16 + ln;
        bfr[nt] = *(const bf16x8*)&Bs[br * BK + (((h * 4 + q) ^ (br & 7)) * 8)];
      }
#pragma unroll
      for (int mt = 0; mt < 4; ++mt)
#pragma unroll
        for (int nt = 0; nt < 4; ++nt)
          acc[mt][nt] = __builtin_amdgcn_mfma_f32_16x16x32_bf16(af[mt], bfr[nt], acc[mt][nt], 0, 0, 0);
    }
  }

#pragma unroll
  for (int mt = 0; mt < 4; ++mt) {
#pragma unroll
    for (int i = 0; i < 4; ++i) {
      int row = m0 + wm * 64 + mt * 16 + q * 4 + i;
#pragma unroll
      for (int nt = 0; nt < 4; ++nt) {
        int col = n0 + wn * 64 + nt * 16 + ln;
        float vv = acc[mt][nt][i];
        if (MODE == 2) { vv += bias[(size_t)(row >> 11) * 2048 + col]; vv = fmaxf(vv, 0.f); }
        if (MODE == 4) {
          vv += bias[col]; vv = fmaxf(vv, 0.f);
          vv += resid[(size_t)row * 2048 + col];
          ((float*)outp)[(size_t)row * ldo + col] = vv;
        } else {
          ((unsigned short*)outp)[(size_t)row * ldo + col] = f2bf(vv);
        }
      }
    }
  }
}

// ============================================================================
// 256x256 8-phase GEMM, READ-AHEAD pipelined (R2; resubmitted R3 after infra
// failure -- pipeline re-audited: barriers uniform, vmcnt accounting proven,
// no OOB, no deadlock mechanism).
//   C[M,N] = A[M,K](bf16,lda) * Bt[N,K](bf16,ldb)^T
//   grid = (N/256, M/256), 512 threads (8 waves, 2M x 4N), 128 KiB LDS.
// R1 post-mortem: same-phase ds_read -> lgkmcnt(0) -> MFMA serializes LDS
// (1536cy/Ktile) with MFMA (2483cy) -> 47% util. R2: every phase issues the
// 6 ds_reads for the NEXT phase's MFMA (banks a0/a1 per K-half, ba/bb
// alternating), so the LDS unit runs under the MFMA pipe and the MFMA wait
// is a counted lgkmcnt, never 0.
// Phase layout per K-tile tt (buf c = tt&1), 16 MFMA each:
//   P1: rd b23(kh0)->bb, a1[0..3]<-As[c][1] | stage A(t+1,kh1)->c^1 | MM(a0,ba)
//   P2: rd a1[4..7], b01(kh1)->ba           | stage B(t+1,kh1)->c^1 | MM(a0,bb)
//   P3: rd b23(kh1)->bb, a0[0..3]<-As[c^1][0]| stage A(t+2,kh0)->c  | MM(a1,ba)
//   P4: rd a0[4..7], b01'->ba <-Bs[c^1][0]  | stage B(t+2,kh0)->c   | MM(a1,bb)
// vmcnt(6) before each closing barrier = 3 half-tiles in flight; every slot
// read is >=4 phases after its stage issue (in-order retire => landed), and
// every overwritten slot's last ds_read completed >=4 phases earlier.
// ============================================================================
#define GLD16(g, s)                                                        \
  __builtin_amdgcn_global_load_lds(                                        \
      (const __attribute__((address_space(1))) void*)(g),                  \
      (__attribute__((address_space(3))) void*)(s), 16, 0, 0)
#define BARX() asm volatile("s_barrier" ::: "memory")
#define VMW6() asm volatile("s_waitcnt vmcnt(6)" ::: "memory")
#define VMW4() asm volatile("s_waitcnt vmcnt(4)" ::: "memory")
#define VMW0() asm volatile("s_waitcnt vmcnt(0)" ::: "memory")

#define LD_A4(areg, base, buf, h)                                          \
  do {                                                                     \
    _Pragma("unroll") for (int _i = 0; _i < 4; ++_i) {                     \
      int ar = wm * 128 + ((base) + _i) * 16 + ln;                         \
      areg[(base) + _i] = *(const bf16x8*)&As[buf][h][ar * 32 + rsel];     \
    }                                                                      \
  } while (0)

#define LD_B2(breg, buf, h, np)                                            \
  do {                                                                     \
    _Pragma("unroll") for (int _i = 0; _i < 2; ++_i) {                     \
      int br = wn * 64 + ((np)*2 + _i) * 16 + ln;                          \
      breg[_i] = *(const bf16x8*)&Bs[buf][h][br * 32 + rsel];              \
    }                                                                      \
  } while (0)

#define MM(areg, breg, np)                                                 \
  do {                                                                     \
    __builtin_amdgcn_s_setprio(1);                                         \
    _Pragma("unroll") for (int _mt = 0; _mt < 8; ++_mt) {                  \
      _Pragma("unroll") for (int _i = 0; _i < 2; ++_i)                     \
          acc[_mt][(np)*2 + _i] = __builtin_amdgcn_mfma_f32_16x16x32_bf16( \
              areg[_mt], breg[_i], acc[_mt][(np)*2 + _i], 0, 0, 0);        \
    }                                                                      \
    __builtin_amdgcn_s_setprio(0);                                         \
  } while (0)

template <int MODE>
__global__ __launch_bounds__(512, 2) void gemm256_kernel(
    const unsigned short* __restrict__ A, int lda,
    const unsigned short* __restrict__ Bt, int ldb, int K,
    void* __restrict__ outp, int ldo,
    const float* __restrict__ bias, const float* __restrict__ resid) {
  __shared__ unsigned short As[2][2][256 * 32];
  __shared__ unsigned short Bs[2][2][256 * 32];
  const int t = threadIdx.x;
  const int wv = t >> 6, l = t & 63;
  const int wm = wv >> 2, wn = wv & 3;   // 2 x 4 wave grid
  const int q = l >> 4, ln = l & 15;

  // XCD-aware swizzle: 256 blocks -> each XCD owns a contiguous 4x8 band.
  const int L = blockIdx.y * 8 + blockIdx.x;
  const int lin = (L & 7) * 32 + (L >> 3);
  const int m0 = (lin >> 3) * 256, n0 = (lin & 7) * 256;

  // staging coords (identical for both 128-row rounds of a half-tile)
  const int srow = t >> 2;                                    // 0..127
  const int scol = (((t & 3) * 16) ^ (((srow >> 1) & 3) << 4)) >> 1;  // elems
  const unsigned short* Abase = A + (size_t)(m0 + srow) * lda + scol;
  const unsigned short* Bbase = Bt + (size_t)(n0 + srow) * ldb + scol;
  const size_t astep = (size_t)128 * lda, bstep = (size_t)128 * ldb;
  const int rsel = (q * 8) ^ (((ln >> 1) & 3) << 3);  // read swizzle (elems)

  f32x4 acc[8][4];
#pragma unroll
  for (int i = 0; i < 8; ++i)
#pragma unroll
    for (int j = 0; j < 4; ++j) acc[i][j] = {0.f, 0.f, 0.f, 0.f};

  auto stageA = [&](int kt, int kh, int buf) {
    const unsigned short* g = Abase + (size_t)kt * 64 + kh * 32;
    GLD16(g, &As[buf][kh][wv * 512]);
    GLD16(g + astep, &As[buf][kh][4096 + wv * 512]);
  };
  auto stageB = [&](int kt, int kh, int buf) {
    const unsigned short* g = Bbase + (size_t)kt * 64 + kh * 32;
    GLD16(g, &Bs[buf][kh][wv * 512]);
    GLD16(g + bstep, &Bs[buf][kh][4096 + wv * 512]);
  };

  bf16x8 a0[8], a1[8], ba[2], bb[2];

  const int NT = K >> 6;
  // prologue: tile0 full + tile1 kh0 (12 loads); wait tile0 landed (leave 4)
  stageA(0, 0, 0); stageB(0, 0, 0);
  stageA(0, 1, 0); stageB(0, 1, 0);
  stageA(1, 0, 1); stageB(1, 0, 1);
  VMW4();
  BARX();
  // pre-read tile0 kh0 fragments (feeds P1/P2 MFMA of tt=0)
  LD_A4(a0, 0, 0, 0);
  LD_A4(a0, 4, 0, 0);
  LD_B2(ba, 0, 0, 0);

  for (int tt = 0; tt < NT; ++tt) {
    const int c = tt & 1;
    const int t1 = (tt + 1 == NT) ? 0 : tt + 1;          // wrap: harmless re-stage
    const int t2 = (tt + 2 >= NT) ? tt + 2 - NT : tt + 2;
    // ---- P1: MM kh0 x nt{0,1}; read-ahead b23(kh0), a1 lo ----
    LD_B2(bb, c, 0, 1);
    LD_A4(a1, 0, c, 1);
    stageA(t1, 1, c ^ 1);
    BARX();
    MM(a0, ba, 0);
    VMW6();
    BARX();
    // ---- P2: MM kh0 x nt{2,3}; read-ahead a1 hi, b01(kh1) ----
    LD_A4(a1, 4, c, 1);
    LD_B2(ba, c, 1, 0);
    stageB(t1, 1, c ^ 1);
    BARX();
    MM(a0, bb, 1);
    VMW6();
    BARX();
    // ---- P3: MM kh1 x nt{0,1}; read-ahead b23(kh1), next a0 lo ----
    LD_B2(bb, c, 1, 1);
    LD_A4(a0, 0, c ^ 1, 0);
    stageA(t2, 0, c);
    BARX();
    MM(a1, ba, 0);
    VMW6();
    BARX();
    // ---- P4: MM kh1 x nt{2,3}; read-ahead next a0 hi, next b01 ----
    LD_A4(a0, 4, c ^ 1, 0);
    LD_B2(ba, c ^ 1, 0, 0);
    stageB(t2, 0, c);
    BARX();
    MM(a1, bb, 1);
    VMW6();
    BARX();
  }
  VMW0();   // drain trailing (wrapped) stages before epilogue / endpgm

#pragma unroll
  for (int mt = 0; mt < 8; ++mt) {
#pragma unroll
    for (int i = 0; i < 4; ++i) {
      int row = m0 + wm * 128 + mt * 16 + q * 4 + i;
#pragma unroll
      for (int nt = 0; nt < 4; ++nt) {
        int col = n0 + wn * 64 + nt * 16 + ln;
        float vv = acc[mt][nt][i];
        if (MODE == 2) { vv += bias[(size_t)(row >> 11) * 2048 + col]; vv = fmaxf(vv, 0.f); }
        if (MODE == 4) {
          vv += bias[col]; vv = fmaxf(vv, 0.f);
          vv += resid[(size_t)row * 2048 + col];
          ((float*)outp)[(size_t)row * ldo + col] = vv;
        } else {
          ((unsigned short*)outp)[(size_t)row * ldo + col] = f2bf(vv);
        }
      }
    }
  }
}

// ---- chunked scan over S of v[b][s][c], fused coef multiply ----
__global__ __launch_bounds__(256) void scan_partial_kernel(
    const unsigned short* __restrict__ v, float* __restrict__ csum) {
  int c = blockIdx.x * 256 + threadIdx.x;
  int chunk = blockIdx.y, b = blockIdx.z;
  const unsigned short* p = v + ((size_t)(b * S_DIM + chunk * CHLEN)) * D_DIM + c;
  float s = 0.f;
#pragma unroll 4
  for (int i = 0; i < CHLEN; ++i) s += bf2f(p[(size_t)i * D_DIM]);
  csum[((size_t)b * NCHUNK + chunk) * D_DIM + c] = s;
}

__global__ __launch_bounds__(256) void scan_offsets_kernel(float* __restrict__ csum) {
  int c = blockIdx.x * 256 + threadIdx.x;
  int b = blockIdx.y;
  float run = 0.f;
  float* p = csum + (size_t)b * NCHUNK * D_DIM + c;
  for (int ch = 0; ch < NCHUNK; ++ch) {
    float tv = p[(size_t)ch * D_DIM];
    p[(size_t)ch * D_DIM] = run;
    run += tv;
  }
}

// writes pooled directly into concat[:, 2048:4096] (ld 4096)
__global__ __launch_bounds__(256) void scan_apply_kernel(
    const unsigned short* __restrict__ v, const float* __restrict__ csum,
    const float* __restrict__ coef, unsigned short* __restrict__ pooled_out) {
  int c = blockIdx.x * 256 + threadIdx.x;
  int chunk = blockIdx.y, b = blockIdx.z;
  int h = c >> 7;
  int row0 = b * S_DIM + chunk * CHLEN;
  float run = csum[((size_t)b * NCHUNK + chunk) * D_DIM + c];
  const unsigned short* vp = v + (size_t)row0 * D_DIM + c;
  unsigned short* po = pooled_out + (size_t)row0 * CONCAT_LD + c;
  const float* cf = coef + (size_t)row0 * H_DIM + h;
#pragma unroll 4
  for (int i = 0; i < CHLEN; ++i) {
    run += bf2f(vp[(size_t)i * D_DIM]);
    po[(size_t)i * CONCAT_LD] = f2bf(cf[(size_t)i * H_DIM] * run);
  }
}

// ---- in-place LayerNorm on d_out rows ----
__global__ __launch_bounds__(256) void ln_kernel(
    float* __restrict__ out, const float* __restrict__ gamma, const float* __restrict__ beta) {
  int row = blockIdx.x, t = threadIdx.x;
  float* pr = out + (size_t)row * D_DIM;
  float vals[8];
  float s = 0.f;
#pragma unroll
  for (int i = 0; i < 8; ++i) { vals[i] = pr[t + i * 256]; s += vals[i]; }
  __shared__ float red[4];
  for (int off = 32; off; off >>= 1) s += __shfl_down(s, off);
  if ((t & 63) == 0) red[t >> 6] = s;
  __syncthreads();
  float mean = (red[0] + red[1] + red[2] + red[3]) * (1.f / D_DIM);
  __syncthreads();
  float c2 = 0.f;
#pragma unroll
  for (int i = 0; i < 8; ++i) { float c = vals[i] - mean; c2 += c * c; }
  for (int off = 32; off; off >>= 1) c2 += __shfl_down(c2, off);
  if ((t & 63) == 0) red[t >> 6] = c2;
  __syncthreads();
  float var = (red[0] + red[1] + red[2] + red[3]) * (1.f / D_DIM);
  float rstd = rsqrtf(var + 1e-6f);
#pragma unroll
  for (int i = 0; i < 8; ++i) {
    int col = t + i * 256;
    pr[col] = (vals[i] - mean) * rstd * gamma[col] + beta[col];
  }
}

extern "C" void kernel_launch(void* const* d_in, const int* in_sizes, int n_in,
                              void* d_out, int out_size, void* d_ws, size_t ws_size,
                              hipStream_t stream) {
  const float* x      = (const float*)d_in[0];
  const float* vector = (const float*)d_in[1];
  const float* W_att  = (const float*)d_in[2];
  const float* temp   = (const float*)d_in[3];
  const float* W_val  = (const float*)d_in[4];
  const float* W_op   = (const float*)d_in[5];
  const float* ff1    = (const float*)d_in[6];
  const float* ff1_b  = (const float*)d_in[7];
  const float* ff2    = (const float*)d_in[8];
  const float* ff2_b  = (const float*)d_in[9];
  const float* gamma  = (const float*)d_in[10];
  const float* beta   = (const float*)d_in[11];
  float* out = (float*)d_out;

  char* ws = (char*)d_ws;
  auto alloc = [&](size_t bytes) {
    char* p = ws; ws += (bytes + 255) & ~(size_t)255; return p;
  };
  unsigned short* concat = (unsigned short*)alloc((size_t)M_ROWS * CONCAT_LD * 2);  // [x | pooled]
  unsigned short* wv_t   = (unsigned short*)alloc((size_t)2048 * 2048 * 2);
  unsigned short* btff1  = (unsigned short*)alloc((size_t)2048 * 4096 * 2);  // [F1a^T | Wc^T] rows n, ld 4096
  unsigned short* f1bT   = (unsigned short*)alloc((size_t)2048 * 2048 * 2);
  unsigned short* wop_bf = (unsigned short*)alloc((size_t)2048 * 2048 * 2);
  unsigned short* ff2_t  = (unsigned short*)alloc((size_t)2048 * 2048 * 2);
  unsigned short* vbuf   = (unsigned short*)alloc((size_t)M_ROWS * 2048 * 2);
  unsigned short* h1     = (unsigned short*)alloc((size_t)M_ROWS * 2048 * 2);
  float* logits = (float*)alloc((size_t)M_ROWS * H_DIM * 4);
  float* coef   = (float*)alloc((size_t)M_ROWS * H_DIM * 4);
  float* csum   = (float*)alloc((size_t)B_DIM * NCHUNK * D_DIM * 4);
  float* part   = (float*)alloc((size_t)16 * 4 * 2048 * 4);
  float* bias2  = (float*)alloc((size_t)4 * 2048 * 4);

  xconv_logits_kernel<<<M_ROWS, 256, 0, stream>>>(x, W_att, concat, logits);
  transpose_conv_kernel<<<dim3(64, 64), 256, 0, stream>>>(W_val, wv_t, 2048, 2048, 2048);
  transpose_conv_kernel<<<dim3(64, 64), 256, 0, stream>>>(ff1, btff1, 2048, 2048, 4096);
  transpose_conv_kernel<<<dim3(64, 64), 256, 0, stream>>>(ff1 + (size_t)2048 * 2048, f1bT, 2048, 2048, 2048);
  convert_kernel<<<2048 * 2048 / 1024, 256, 0, stream>>>(W_op, wop_bf);
  transpose_conv_kernel<<<dim3(64, 64), 256, 0, stream>>>(ff2, ff2_t, 2048, 2048, 2048);
  coef_kernel<<<B_DIM * H_DIM, 256, 0, stream>>>(logits, temp, coef);
  // Wc^T[n][i] = (F1b^T @ W_op^T)[n][i] -> btff1[:, 2048:4096]  (small: keep 128^2)
  gemm_bt_kernel<1><<<dim3(16, 16), 256, 0, stream>>>(
      f1bT, 2048, wop_bf, 2048, 2048, btff1 + 2048, 4096, nullptr, nullptr);
  // bias2 = vector @ F1b + ff1_b
  bias2_partial_kernel<<<dim3(8, 16, 4), 256, 0, stream>>>(vector, ff1, part);
  bias2_reduce_kernel<<<dim3(8, 4), 256, 0, stream>>>(part, ff1_b, bias2);
  // v = x @ W_values   (256^2 read-ahead)
  gemm256_kernel<1><<<dim3(8, 32), 512, 0, stream>>>(
      concat, CONCAT_LD, wv_t, 2048, 2048, vbuf, 2048, nullptr, nullptr);
  scan_partial_kernel<<<dim3(8, NCHUNK, B_DIM), 256, 0, stream>>>(vbuf, csum);
  scan_offsets_kernel<<<dim3(8, B_DIM), 256, 0, stream>>>(csum);
  scan_apply_kernel<<<dim3(8, NCHUNK, B_DIM), 256, 0, stream>>>(vbuf, csum, coef, concat + 2048);
  // h1 = relu([x|pooled] @ [F1a;Wc] + bias2[b])   (256^2 read-ahead, K=4096)
  gemm256_kernel<2><<<dim3(8, 32), 512, 0, stream>>>(
      concat, CONCAT_LD, btff1, 4096, 4096, h1, 2048, bias2, nullptr);
  // out = relu(h1 @ ff2 + ff2_b) + x   (256^2 read-ahead)
  gemm256_kernel<4><<<dim3(8, 32), 512, 0, stream>>>(
      h1, 2048, ff2_t, 2048, 2048, out, 2048, ff2_b, x);
  ln_kernel<<<M_ROWS, 256, 0, stream>>>(out, gamma, beta);
}

// Round 4
// 718.166 us; speedup vs baseline: 1.0004x; 1.0004x over previous
//
#include <hip/hip_runtime.h>
#include <stdint.h>

#define B_DIM 4
#define S_DIM 2048
#define D_DIM 2048
#define H_DIM 16
#define M_ROWS (B_DIM * S_DIM)   // 8192
#define CONCAT_LD 4096
#define NCHUNK 32
#define CHLEN (S_DIM / NCHUNK)   // 64

#define BM 128
#define BN 128
#define BK 64

typedef __attribute__((ext_vector_type(8))) __bf16 bf16x8;
typedef __attribute__((ext_vector_type(4))) float f32x4;

__device__ inline unsigned short f2bf(float f) {
  union { float f; unsigned u; } x; x.f = f;
  unsigned r = x.u + 0x7fffu + ((x.u >> 16) & 1u);
  return (unsigned short)(r >> 16);
}
__device__ inline float bf2f(unsigned short s) {
  union { unsigned u; float f; } x; x.u = ((unsigned)s) << 16;
  return x.f;
}

// ---- fused: x fp32 -> bf16 into concat[:,0:2048]  AND  logits = x @ W_att ----
__global__ __launch_bounds__(256) void xconv_logits_kernel(
    const float* __restrict__ x, const float* __restrict__ Watt,
    unsigned short* __restrict__ concat, float* __restrict__ logits) {
  int row = blockIdx.x, t = threadIdx.x;
  const float* xr = x + (size_t)row * D_DIM;
  unsigned short* cr = concat + (size_t)row * CONCAT_LD;
  float p[H_DIM];
#pragma unroll
  for (int h = 0; h < H_DIM; ++h) p[h] = 0.f;
#pragma unroll
  for (int i = 0; i < 8; ++i) {
    int k = t + i * 256;
    float xv = xr[k];
    cr[k] = f2bf(xv);
    const float* wr = Watt + (size_t)k * H_DIM;
#pragma unroll
    for (int h = 0; h < H_DIM; ++h) p[h] += xv * wr[h];
  }
  __shared__ float red[4][H_DIM];
  int l = t & 63, w = t >> 6;
#pragma unroll
  for (int h = 0; h < H_DIM; ++h) {
    float v = p[h];
    for (int off = 32; off; off >>= 1) v += __shfl_down(v, off);
    if (l == 0) red[w][h] = v;
  }
  __syncthreads();
  if (t < H_DIM)
    logits[(size_t)row * H_DIM + t] = red[0][t] + red[1][t] + red[2][t] + red[3][t];
}

// ---- fused weight prep: 4 transposes (fp32->bf16^T) + 1 convert ----
// z=0: W_val -> wv_t (ld 2048); z=1: ff1[0:2048] -> btff1 (ld 4096);
// z=2: ff1[2048:4096] -> f1bT (ld 2048); z=3: ff2 -> ff2_t (ld 2048);
// z=4: W_op -> wop_bf (plain convert).
__global__ __launch_bounds__(256) void prep_kernel(
    const float* __restrict__ Wval, const float* __restrict__ ff1,
    const float* __restrict__ ff2, const float* __restrict__ Wop,
    unsigned short* __restrict__ wv_t, unsigned short* __restrict__ btff1,
    unsigned short* __restrict__ f1bT, unsigned short* __restrict__ ff2_t,
    unsigned short* __restrict__ wop_bf) {
  int z = blockIdx.z;
  if (z == 4) {
    size_t idx = (((size_t)blockIdx.y * 64 + blockIdx.x) * 256 + threadIdx.x) * 4;
    const float4 v = *(const float4*)(Wop + idx);
    ushort4 o;
    o.x = f2bf(v.x); o.y = f2bf(v.y); o.z = f2bf(v.z); o.w = f2bf(v.w);
    *(ushort4*)(wop_bf + idx) = o;
    return;
  }
  const float* src;
  unsigned short* dst;
  int ldd;
  if (z == 0)      { src = Wval;                        dst = wv_t;  ldd = 2048; }
  else if (z == 1) { src = ff1;                         dst = btff1; ldd = 4096; }
  else if (z == 2) { src = ff1 + (size_t)2048 * 2048;   dst = f1bT;  ldd = 2048; }
  else             { src = ff2;                         dst = ff2_t; ldd = 2048; }
  __shared__ float tile[32][33];
  int c0 = blockIdx.x * 32, r0 = blockIdx.y * 32;
  int tx = threadIdx.x & 31, ty = threadIdx.x >> 5;
#pragma unroll
  for (int i = 0; i < 32; i += 8)
    tile[ty + i][tx] = src[(size_t)(r0 + ty + i) * 2048 + c0 + tx];
  __syncthreads();
#pragma unroll
  for (int i = 0; i < 32; i += 8)
    dst[(size_t)(c0 + ty + i) * ldd + r0 + tx] = f2bf(tile[tx][ty + i]);
}

// ---- per (b,h): max over s, then coef = w/(w*(s+1)+1e-30), w=exp((lg-mx)*T) ----
__global__ __launch_bounds__(256) void coef_kernel(
    const float* __restrict__ logits, const float* __restrict__ temp, float* __restrict__ coef) {
  int b = blockIdx.x >> 4, h = blockIdx.x & 15;
  int t = threadIdx.x;
  const float* lg = logits + (size_t)b * S_DIM * H_DIM + h;
  float mx = -1e30f;
  for (int s = t; s < S_DIM; s += 256) mx = fmaxf(mx, lg[(size_t)s * H_DIM]);
  for (int off = 32; off; off >>= 1) mx = fmaxf(mx, __shfl_down(mx, off));
  __shared__ float red[4];
  if ((t & 63) == 0) red[t >> 6] = mx;
  __syncthreads();
  mx = fmaxf(fmaxf(red[0], red[1]), fmaxf(red[2], red[3]));
  float T = temp[h];
  float* cf = coef + (size_t)b * S_DIM * H_DIM + h;
  for (int s = t; s < S_DIM; s += 256) {
    float w = expf((lg[(size_t)s * H_DIM] - mx) * T);
    cf[(size_t)s * H_DIM] = w / (w * (float)(s + 1) + 1e-30f);
  }
}

// ---- bias2 = vector @ F1b (+ ff1_b), partial over j-segments then reduce ----
__global__ __launch_bounds__(256) void bias2_partial_kernel(
    const float* __restrict__ vector, const float* __restrict__ ff1,
    float* __restrict__ part) {
  int n = blockIdx.x * 256 + threadIdx.x;
  int seg = blockIdx.y, b = blockIdx.z;
  const float* vr = vector + (size_t)b * 2048 + seg * 128;
  const float* fr = ff1 + (size_t)(2048 + seg * 128) * 2048 + n;
  float acc = 0.f;
#pragma unroll 8
  for (int j = 0; j < 128; ++j) acc += vr[j] * fr[(size_t)j * 2048];
  part[((size_t)seg * 4 + b) * 2048 + n] = acc;
}

__global__ __launch_bounds__(256) void bias2_reduce_kernel(
    const float* __restrict__ part, const float* __restrict__ ff1_b,
    float* __restrict__ bias2) {
  int n = blockIdx.x * 256 + threadIdx.x;
  int b = blockIdx.y;
  float acc = ff1_b[n];
#pragma unroll
  for (int s = 0; s < 16; ++s) acc += part[((size_t)s * 4 + b) * 2048 + n];
  bias2[(size_t)b * 2048 + n] = acc;
}

// ---- 128x128 GEMM (m97 structure) -- kept for the small 2048^3 Wc GEMM ----
template <int MODE>
__global__ __launch_bounds__(256) void gemm_bt_kernel(
    const unsigned short* __restrict__ A, int lda,
    const unsigned short* __restrict__ Bt, int ldb, int K,
    void* __restrict__ outp, int ldo,
    const float* __restrict__ bias, const float* __restrict__ resid) {
  __shared__ unsigned short As[BM * BK];
  __shared__ unsigned short Bs[BN * BK];
  const int t = threadIdx.x;
  const int w = t >> 6, l = t & 63;
  const int wm = w & 1, wn = w >> 1;
  const int q = l >> 4, ln = l & 15;

  const int L = blockIdx.y * 16 + blockIdx.x;
  const int xcd = L & 7;
  const int W = L >> 3;
  const int bx = W & 15;
  const int by = (W >> 4) * 8 + xcd;
  const int m0 = by * BM, n0 = bx * BN;

  f32x4 acc[4][4];
#pragma unroll
  for (int i = 0; i < 4; ++i)
#pragma unroll
    for (int j = 0; j < 4; ++j) acc[i][j] = {0.f, 0.f, 0.f, 0.f};

  for (int k0 = 0; k0 < K; k0 += BK) {
    __syncthreads();
#pragma unroll
    for (int r = 0; r < 4; ++r) {
      int s = r * 256 + t;
      int row = s >> 3;
      int ch = (s & 7) ^ (row & 7);
      const unsigned short* ga = A + (size_t)(m0 + row) * lda + k0 + ch * 8;
      __builtin_amdgcn_global_load_lds(
          (const __attribute__((address_space(1))) void*)ga,
          (__attribute__((address_space(3))) void*)(As + (r * 256 + w * 64) * 8), 16, 0, 0);
      const unsigned short* gb = Bt + (size_t)(n0 + row) * ldb + k0 + ch * 8;
      __builtin_amdgcn_global_load_lds(
          (const __attribute__((address_space(1))) void*)gb,
          (__attribute__((address_space(3))) void*)(Bs + (r * 256 + w * 64) * 8), 16, 0, 0);
    }
    __syncthreads();
#pragma unroll
    for (int h = 0; h < 2; ++h) {
      bf16x8 af[4], bfr[4];
#pragma unroll
      for (int mt = 0; mt < 4; ++mt) {
        int ar = wm * 64 + mt * 16 + ln;
        af[mt] = *(const bf16x8*)&As[ar * BK + (((h * 4 + q) ^ (ar & 7)) * 8)];
      }
#pragma unroll
      for (int nt = 0; nt < 4; ++nt) {
        int br = wn * 64 + nt * 16 + ln;
        bfr[nt] = *(const bf16x8*)&Bs[br * BK + (((h * 4 + q) ^ (br & 7)) * 8)];
      }
#pragma unroll
      for (int mt = 0; mt < 4; ++mt)
#pragma unroll
        for (int nt = 0; nt < 4; ++nt)
          acc[mt][nt] = __builtin_amdgcn_mfma_f32_16x16x32_bf16(af[mt], bfr[nt], acc[mt][nt], 0, 0, 0);
    }
  }

#pragma unroll
  for (int mt = 0; mt < 4; ++mt) {
#pragma unroll
    for (int i = 0; i < 4; ++i) {
      int row = m0 + wm * 64 + mt * 16 + q * 4 + i;
#pragma unroll
      for (int nt = 0; nt < 4; ++nt) {
        int col = n0 + wn * 64 + nt * 16 + ln;
        float vv = acc[mt][nt][i];
        if (MODE == 2) { vv += bias[(size_t)(row >> 11) * 2048 + col]; vv = fmaxf(vv, 0.f); }
        if (MODE == 4) {
          vv += bias[col]; vv = fmaxf(vv, 0.f);
          vv += resid[(size_t)row * 2048 + col];
          ((float*)outp)[(size_t)row * ldo + col] = vv;
        } else {
          ((unsigned short*)outp)[(size_t)row * ldo + col] = f2bf(vv);
        }
      }
    }
  }
}

// ============================================================================
// 256x256 GEMM, m201-style same-phase consume, BALANCED 8/4/8/4 reads (R4).
// R1 (10/2/10/2 reads, same skeleton) = 127.5us / 47% MfmaUtil -- verified.
// R2 read-ahead regressed (compiler can't carry lgkm credit across asm
// "memory" barriers -> conservative drain). R4 keeps R1's verified skeleton
// and staging ring, but decomposes each phase as (m-half x k-half) with
// B-register reuse across the phase pair:
//   P1: rd aL(4)+bk(4) from [c][0] | stage A(t+1,kh1)->c^1 | MM rows0-3
//   P2: rd aH(4), reuse bk         | stage B(t+1,kh1)->c^1 | MM rows4-7  VMW6
//   P3: rd aL(4)+bk(4) from [c][1] | stage A(t+2,kh0)->c   | MM rows0-3
//   P4: rd aH(4), reuse bk         | stage B(t+2,kh0)->c   | MM rows4-7  VMW6
// Safety audit (as R1, passed): VMW6+BARX at P2/P4 retires every staged
// half-tile >=1 full wait-barrier before its first ds_read; every slot
// overwrite post-dates the last reader's phase-closing barrier.
// ============================================================================
#define GLD16(g, s)                                                        \
  __builtin_amdgcn_global_load_lds(                                        \
      (const __attribute__((address_space(1))) void*)(g),                  \
      (__attribute__((address_space(3))) void*)(s), 16, 0, 0)
#define BARX() asm volatile("s_barrier" ::: "memory")
#define VMW6() asm volatile("s_waitcnt vmcnt(6)" ::: "memory")
#define VMW4() asm volatile("s_waitcnt vmcnt(4)" ::: "memory")
#define VMW0() asm volatile("s_waitcnt vmcnt(0)" ::: "memory")

#define LD_A4(areg, buf, h, mbase)                                         \
  do {                                                                     \
    _Pragma("unroll") for (int _i = 0; _i < 4; ++_i) {                     \
      int ar = wm * 128 + ((mbase) + _i) * 16 + ln;                        \
      areg[_i] = *(const bf16x8*)&As[buf][h][ar * 32 + rsel];              \
    }                                                                      \
  } while (0)

#define LD_B4(buf, h)                                                      \
  do {                                                                     \
    _Pragma("unroll") for (int _i = 0; _i < 4; ++_i) {                     \
      int br = wn * 64 + _i * 16 + ln;                                     \
      bk[_i] = *(const bf16x8*)&Bs[buf][h][br * 32 + rsel];                \
    }                                                                      \
  } while (0)

#define MMR(areg, rowbase)                                                 \
  do {                                                                     \
    __builtin_amdgcn_s_setprio(1);                                         \
    _Pragma("unroll") for (int _j = 0; _j < 4; ++_j) {                     \
      _Pragma("unroll") for (int _n = 0; _n < 4; ++_n)                     \
          acc[(rowbase) + _j][_n] = __builtin_amdgcn_mfma_f32_16x16x32_bf16( \
              areg[_j], bk[_n], acc[(rowbase) + _j][_n], 0, 0, 0);         \
    }                                                                      \
    __builtin_amdgcn_s_setprio(0);                                         \
  } while (0)

template <int MODE>
__global__ __launch_bounds__(512, 2) void gemm256_kernel(
    const unsigned short* __restrict__ A, int lda,
    const unsigned short* __restrict__ Bt, int ldb, int K,
    void* __restrict__ outp, int ldo,
    const float* __restrict__ bias, const float* __restrict__ resid) {
  __shared__ unsigned short As[2][2][256 * 32];
  __shared__ unsigned short Bs[2][2][256 * 32];
  const int t = threadIdx.x;
  const int wv = t >> 6, l = t & 63;
  const int wm = wv >> 2, wn = wv & 3;   // 2 x 4 wave grid
  const int q = l >> 4, ln = l & 15;

  // XCD-aware swizzle: 256 blocks -> each XCD owns a contiguous 4x8 band.
  const int L = blockIdx.y * 8 + blockIdx.x;
  const int lin = (L & 7) * 32 + (L >> 3);
  const int m0 = (lin >> 3) * 256, n0 = (lin & 7) * 256;

  // staging coords (identical for both 128-row rounds of a half-tile)
  const int srow = t >> 2;                                    // 0..127
  const int scol = (((t & 3) * 16) ^ (((srow >> 1) & 3) << 4)) >> 1;  // elems
  const unsigned short* Abase = A + (size_t)(m0 + srow) * lda + scol;
  const unsigned short* Bbase = Bt + (size_t)(n0 + srow) * ldb + scol;
  const size_t astep = (size_t)128 * lda, bstep = (size_t)128 * ldb;
  const int rsel = (q * 8) ^ (((ln >> 1) & 3) << 3);  // read swizzle (elems)

  f32x4 acc[8][4];
#pragma unroll
  for (int i = 0; i < 8; ++i)
#pragma unroll
    for (int j = 0; j < 4; ++j) acc[i][j] = {0.f, 0.f, 0.f, 0.f};

  auto stageA = [&](int kt, int kh, int buf) {
    const unsigned short* g = Abase + (size_t)kt * 64 + kh * 32;
    GLD16(g, &As[buf][kh][wv * 512]);
    GLD16(g + astep, &As[buf][kh][4096 + wv * 512]);
  };
  auto stageB = [&](int kt, int kh, int buf) {
    const unsigned short* g = Bbase + (size_t)kt * 64 + kh * 32;
    GLD16(g, &Bs[buf][kh][wv * 512]);
    GLD16(g + bstep, &Bs[buf][kh][4096 + wv * 512]);
  };

  bf16x8 aL[4], aH[4], bk[4];

  const int NT = K >> 6;
  // prologue: tile0 full + tile1 kh0 (12 loads); wait tile0 landed (leave 4)
  stageA(0, 0, 0); stageB(0, 0, 0);
  stageA(0, 1, 0); stageB(0, 1, 0);
  stageA(1, 0, 1); stageB(1, 0, 1);
  VMW4();
  BARX();

  for (int tt = 0; tt < NT; ++tt) {
    const int c = tt & 1;
    const int t1 = (tt + 1 == NT) ? 0 : tt + 1;          // wrap: harmless re-stage
    const int t2 = (tt + 2 >= NT) ? tt + 2 - NT : tt + 2;
    // ---- P1: kh0, m-rows 0-3 ----
    LD_A4(aL, c, 0, 0);
    LD_B4(c, 0);
    stageA(t1, 1, c ^ 1);
    BARX();
    MMR(aL, 0);
    BARX();
    // ---- P2: kh0, m-rows 4-7 (reuse bk) ----
    LD_A4(aH, c, 0, 4);
    stageB(t1, 1, c ^ 1);
    BARX();
    MMR(aH, 4);
    VMW6();
    BARX();
    // ---- P3: kh1, m-rows 0-3 ----
    LD_A4(aL, c, 1, 0);
    LD_B4(c, 1);
    stageA(t2, 0, c);
    BARX();
    MMR(aL, 0);
    BARX();
    // ---- P4: kh1, m-rows 4-7 (reuse bk) ----
    LD_A4(aH, c, 1, 4);
    stageB(t2, 0, c);
    BARX();
    MMR(aH, 4);
    VMW6();
    BARX();
  }
  VMW0();   // drain trailing (wrapped) stages before epilogue / endpgm

#pragma unroll
  for (int mt = 0; mt < 8; ++mt) {
#pragma unroll
    for (int i = 0; i < 4; ++i) {
      int row = m0 + wm * 128 + mt * 16 + q * 4 + i;
#pragma unroll
      for (int nt = 0; nt < 4; ++nt) {
        int col = n0 + wn * 64 + nt * 16 + ln;
        float vv = acc[mt][nt][i];
        if (MODE == 2) { vv += bias[(size_t)(row >> 11) * 2048 + col]; vv = fmaxf(vv, 0.f); }
        if (MODE == 4) {
          vv += bias[col]; vv = fmaxf(vv, 0.f);
          vv += resid[(size_t)row * 2048 + col];
          ((float*)outp)[(size_t)row * ldo + col] = vv;
        } else {
          ((unsigned short*)outp)[(size_t)row * ldo + col] = f2bf(vv);
        }
      }
    }
  }
}

// ---- chunked scan over S of v[b][s][c] ----
__global__ __launch_bounds__(256) void scan_partial_kernel(
    const unsigned short* __restrict__ v, float* __restrict__ csum) {
  int c = blockIdx.x * 256 + threadIdx.x;
  int chunk = blockIdx.y, b = blockIdx.z;
  const unsigned short* p = v + ((size_t)(b * S_DIM + chunk * CHLEN)) * D_DIM + c;
  float s = 0.f;
#pragma unroll 4
  for (int i = 0; i < CHLEN; ++i) s += bf2f(p[(size_t)i * D_DIM]);
  csum[((size_t)b * NCHUNK + chunk) * D_DIM + c] = s;
}

// writes pooled directly into concat[:, 2048:4096] (ld 4096).
// Computes its own chunk-prefix from csum partials (scan_offsets removed).
__global__ __launch_bounds__(256) void scan_apply_kernel(
    const unsigned short* __restrict__ v, const float* __restrict__ csum,
    const float* __restrict__ coef, unsigned short* __restrict__ pooled_out) {
  int c = blockIdx.x * 256 + threadIdx.x;
  int chunk = blockIdx.y, b = blockIdx.z;
  int h = c >> 7;
  int row0 = b * S_DIM + chunk * CHLEN;
  const float* cs = csum + (size_t)b * NCHUNK * D_DIM + c;
  float run = 0.f;
  for (int j = 0; j < chunk; ++j) run += cs[(size_t)j * D_DIM];
  const unsigned short* vp = v + (size_t)row0 * D_DIM + c;
  unsigned short* po = pooled_out + (size_t)row0 * CONCAT_LD + c;
  const float* cf = coef + (size_t)row0 * H_DIM + h;
#pragma unroll 4
  for (int i = 0; i < CHLEN; ++i) {
    run += bf2f(vp[(size_t)i * D_DIM]);
    po[(size_t)i * CONCAT_LD] = f2bf(cf[(size_t)i * H_DIM] * run);
  }
}

// ---- in-place LayerNorm on d_out rows ----
__global__ __launch_bounds__(256) void ln_kernel(
    float* __restrict__ out, const float* __restrict__ gamma, const float* __restrict__ beta) {
  int row = blockIdx.x, t = threadIdx.x;
  float* pr = out + (size_t)row * D_DIM;
  float vals[8];
  float s = 0.f;
#pragma unroll
  for (int i = 0; i < 8; ++i) { vals[i] = pr[t + i * 256]; s += vals[i]; }
  __shared__ float red[4];
  for (int off = 32; off; off >>= 1) s += __shfl_down(s, off);
  if ((t & 63) == 0) red[t >> 6] = s;
  __syncthreads();
  float mean = (red[0] + red[1] + red[2] + red[3]) * (1.f / D_DIM);
  __syncthreads();
  float c2 = 0.f;
#pragma unroll
  for (int i = 0; i < 8; ++i) { float c = vals[i] - mean; c2 += c * c; }
  for (int off = 32; off; off >>= 1) c2 += __shfl_down(c2, off);
  if ((t & 63) == 0) red[t >> 6] = c2;
  __syncthreads();
  float var = (red[0] + red[1] + red[2] + red[3]) * (1.f / D_DIM);
  float rstd = rsqrtf(var + 1e-6f);
#pragma unroll
  for (int i = 0; i < 8; ++i) {
    int col = t + i * 256;
    pr[col] = (vals[i] - mean) * rstd * gamma[col] + beta[col];
  }
}

extern "C" void kernel_launch(void* const* d_in, const int* in_sizes, int n_in,
                              void* d_out, int out_size, void* d_ws, size_t ws_size,
                              hipStream_t stream) {
  const float* x      = (const float*)d_in[0];
  const float* vector = (const float*)d_in[1];
  const float* W_att  = (const float*)d_in[2];
  const float* temp   = (const float*)d_in[3];
  const float* W_val  = (const float*)d_in[4];
  const float* W_op   = (const float*)d_in[5];
  const float* ff1    = (const float*)d_in[6];
  const float* ff1_b  = (const float*)d_in[7];
  const float* ff2    = (const float*)d_in[8];
  const float* ff2_b  = (const float*)d_in[9];
  const float* gamma  = (const float*)d_in[10];
  const float* beta   = (const float*)d_in[11];
  float* out = (float*)d_out;

  char* ws = (char*)d_ws;
  auto alloc = [&](size_t bytes) {
    char* p = ws; ws += (bytes + 255) & ~(size_t)255; return p;
  };
  unsigned short* concat = (unsigned short*)alloc((size_t)M_ROWS * CONCAT_LD * 2);  // [x | pooled]
  unsigned short* wv_t   = (unsigned short*)alloc((size_t)2048 * 2048 * 2);
  unsigned short* btff1  = (unsigned short*)alloc((size_t)2048 * 4096 * 2);  // [F1a^T | Wc^T] rows n, ld 4096
  unsigned short* f1bT   = (unsigned short*)alloc((size_t)2048 * 2048 * 2);
  unsigned short* wop_bf = (unsigned short*)alloc((size_t)2048 * 2048 * 2);
  unsigned short* ff2_t  = (unsigned short*)alloc((size_t)2048 * 2048 * 2);
  unsigned short* vbuf   = (unsigned short*)alloc((size_t)M_ROWS * 2048 * 2);
  unsigned short* h1     = (unsigned short*)alloc((size_t)M_ROWS * 2048 * 2);
  float* logits = (float*)alloc((size_t)M_ROWS * H_DIM * 4);
  float* coef   = (float*)alloc((size_t)M_ROWS * H_DIM * 4);
  float* csum   = (float*)alloc((size_t)B_DIM * NCHUNK * D_DIM * 4);
  float* part   = (float*)alloc((size_t)16 * 4 * 2048 * 4);
  float* bias2  = (float*)alloc((size_t)4 * 2048 * 4);

  prep_kernel<<<dim3(64, 64, 5), 256, 0, stream>>>(
      W_val, ff1, ff2, W_op, wv_t, btff1, f1bT, ff2_t, wop_bf);
  xconv_logits_kernel<<<M_ROWS, 256, 0, stream>>>(x, W_att, concat, logits);
  coef_kernel<<<B_DIM * H_DIM, 256, 0, stream>>>(logits, temp, coef);
  // Wc^T[n][i] = (F1b^T @ W_op^T)[n][i] -> btff1[:, 2048:4096]  (small: keep 128^2)
  gemm_bt_kernel<1><<<dim3(16, 16), 256, 0, stream>>>(
      f1bT, 2048, wop_bf, 2048, 2048, btff1 + 2048, 4096, nullptr, nullptr);
  // bias2 = vector @ F1b + ff1_b
  bias2_partial_kernel<<<dim3(8, 16, 4), 256, 0, stream>>>(vector, ff1, part);
  bias2_reduce_kernel<<<dim3(8, 4), 256, 0, stream>>>(part, ff1_b, bias2);
  // v = x @ W_values   (256^2 balanced)
  gemm256_kernel<1><<<dim3(8, 32), 512, 0, stream>>>(
      concat, CONCAT_LD, wv_t, 2048, 2048, vbuf, 2048, nullptr, nullptr);
  scan_partial_kernel<<<dim3(8, NCHUNK, B_DIM), 256, 0, stream>>>(vbuf, csum);
  scan_apply_kernel<<<dim3(8, NCHUNK, B_DIM), 256, 0, stream>>>(vbuf, csum, coef, concat + 2048);
  // h1 = relu([x|pooled] @ [F1a;Wc] + bias2[b])   (256^2 balanced, K=4096)
  gemm256_kernel<2><<<dim3(8, 32), 512, 0, stream>>>(
      concat, CONCAT_LD, btff1, 4096, 4096, h1, 2048, bias2, nullptr);
  // out = relu(h1 @ ff2 + ff2_b) + x   (256^2 balanced)
  gemm256_kernel<4><<<dim3(8, 32), 512, 0, stream>>>(
      h1, 2048, ff2_t, 2048, 2048, out, 2048, ff2_b, x);
  ln_kernel<<<M_ROWS, 256, 0, stream>>>(out, gamma, beta);
}

// Round 5
// 651.426 us; speedup vs baseline: 1.1029x; 1.1025x over previous
//
#include <hip/hip_runtime.h>
#include <stdint.h>

#define B_DIM 4
#define S_DIM 2048
#define D_DIM 2048
#define H_DIM 16
#define M_ROWS (B_DIM * S_DIM)   // 8192
#define CONCAT_LD 4096
#define NCHUNK 32
#define CHLEN (S_DIM / NCHUNK)   // 64

#define BM 128
#define BN 128
#define BK 64

typedef __attribute__((ext_vector_type(8))) __bf16 bf16x8;
typedef __attribute__((ext_vector_type(4))) float f32x4;

__device__ inline unsigned short f2bf(float f) {
  union { float f; unsigned u; } x; x.f = f;
  unsigned r = x.u + 0x7fffu + ((x.u >> 16) & 1u);
  return (unsigned short)(r >> 16);
}
__device__ inline float bf2f(unsigned short s) {
  union { unsigned u; float f; } x; x.u = ((unsigned)s) << 16;
  return x.f;
}

// ---- fused: x fp32 -> bf16 into concat[:,0:2048]  AND  logits = x @ W_att ----
__global__ __launch_bounds__(256) void xconv_logits_kernel(
    const float* __restrict__ x, const float* __restrict__ Watt,
    unsigned short* __restrict__ concat, float* __restrict__ logits) {
  int row = blockIdx.x, t = threadIdx.x;
  const float* xr = x + (size_t)row * D_DIM;
  unsigned short* cr = concat + (size_t)row * CONCAT_LD;
  float p[H_DIM];
#pragma unroll
  for (int h = 0; h < H_DIM; ++h) p[h] = 0.f;
#pragma unroll
  for (int i = 0; i < 8; ++i) {
    int k = t + i * 256;
    float xv = xr[k];
    cr[k] = f2bf(xv);
    const float* wr = Watt + (size_t)k * H_DIM;
#pragma unroll
    for (int h = 0; h < H_DIM; ++h) p[h] += xv * wr[h];
  }
  __shared__ float red[4][H_DIM];
  int l = t & 63, w = t >> 6;
#pragma unroll
  for (int h = 0; h < H_DIM; ++h) {
    float v = p[h];
    for (int off = 32; off; off >>= 1) v += __shfl_down(v, off);
    if (l == 0) red[w][h] = v;
  }
  __syncthreads();
  if (t < H_DIM)
    logits[(size_t)row * H_DIM + t] = red[0][t] + red[1][t] + red[2][t] + red[3][t];
}

// ---- fused weight prep: 4 transposes (fp32->bf16^T) + 1 convert ----
__global__ __launch_bounds__(256) void prep_kernel(
    const float* __restrict__ Wval, const float* __restrict__ ff1,
    const float* __restrict__ ff2, const float* __restrict__ Wop,
    unsigned short* __restrict__ wv_t, unsigned short* __restrict__ btff1,
    unsigned short* __restrict__ f1bT, unsigned short* __restrict__ ff2_t,
    unsigned short* __restrict__ wop_bf) {
  int z = blockIdx.z;
  if (z == 4) {
    size_t idx = (((size_t)blockIdx.y * 64 + blockIdx.x) * 256 + threadIdx.x) * 4;
    const float4 v = *(const float4*)(Wop + idx);
    ushort4 o;
    o.x = f2bf(v.x); o.y = f2bf(v.y); o.z = f2bf(v.z); o.w = f2bf(v.w);
    *(ushort4*)(wop_bf + idx) = o;
    return;
  }
  const float* src;
  unsigned short* dst;
  int ldd;
  if (z == 0)      { src = Wval;                        dst = wv_t;  ldd = 2048; }
  else if (z == 1) { src = ff1;                         dst = btff1; ldd = 4096; }
  else if (z == 2) { src = ff1 + (size_t)2048 * 2048;   dst = f1bT;  ldd = 2048; }
  else             { src = ff2;                         dst = ff2_t; ldd = 2048; }
  __shared__ float tile[32][33];
  int c0 = blockIdx.x * 32, r0 = blockIdx.y * 32;
  int tx = threadIdx.x & 31, ty = threadIdx.x >> 5;
#pragma unroll
  for (int i = 0; i < 32; i += 8)
    tile[ty + i][tx] = src[(size_t)(r0 + ty + i) * 2048 + c0 + tx];
  __syncthreads();
#pragma unroll
  for (int i = 0; i < 32; i += 8)
    dst[(size_t)(c0 + ty + i) * ldd + r0 + tx] = f2bf(tile[tx][ty + i]);
}

// ---- per (b,h): max over s, then coef = w/(w*(s+1)+1e-30), w=exp((lg-mx)*T) ----
__global__ __launch_bounds__(256) void coef_kernel(
    const float* __restrict__ logits, const float* __restrict__ temp, float* __restrict__ coef) {
  int b = blockIdx.x >> 4, h = blockIdx.x & 15;
  int t = threadIdx.x;
  const float* lg = logits + (size_t)b * S_DIM * H_DIM + h;
  float mx = -1e30f;
  for (int s = t; s < S_DIM; s += 256) mx = fmaxf(mx, lg[(size_t)s * H_DIM]);
  for (int off = 32; off; off >>= 1) mx = fmaxf(mx, __shfl_down(mx, off));
  __shared__ float red[4];
  if ((t & 63) == 0) red[t >> 6] = mx;
  __syncthreads();
  mx = fmaxf(fmaxf(red[0], red[1]), fmaxf(red[2], red[3]));
  float T = temp[h];
  float* cf = coef + (size_t)b * S_DIM * H_DIM + h;
  for (int s = t; s < S_DIM; s += 256) {
    float w = expf((lg[(size_t)s * H_DIM] - mx) * T);
    cf[(size_t)s * H_DIM] = w / (w * (float)(s + 1) + 1e-30f);
  }
}

// ---- bias2 = vector @ F1b (+ ff1_b), partial over j-segments then reduce ----
__global__ __launch_bounds__(256) void bias2_partial_kernel(
    const float* __restrict__ vector, const float* __restrict__ ff1,
    float* __restrict__ part) {
  int n = blockIdx.x * 256 + threadIdx.x;
  int seg = blockIdx.y, b = blockIdx.z;
  const float* vr = vector + (size_t)b * 2048 + seg * 128;
  const float* fr = ff1 + (size_t)(2048 + seg * 128) * 2048 + n;
  float acc = 0.f;
#pragma unroll 8
  for (int j = 0; j < 128; ++j) acc += vr[j] * fr[(size_t)j * 2048];
  part[((size_t)seg * 4 + b) * 2048 + n] = acc;
}

__global__ __launch_bounds__(256) void bias2_reduce_kernel(
    const float* __restrict__ part, const float* __restrict__ ff1_b,
    float* __restrict__ bias2) {
  int n = blockIdx.x * 256 + threadIdx.x;
  int b = blockIdx.y;
  float acc = ff1_b[n];
#pragma unroll
  for (int s = 0; s < 16; ++s) acc += part[((size_t)s * 4 + b) * 2048 + n];
  bias2[(size_t)b * 2048 + n] = acc;
}

// ---- 128x128 GEMM (m97 structure) -- kept for the small 2048^3 Wc GEMM ----
template <int MODE>
__global__ __launch_bounds__(256) void gemm_bt_kernel(
    const unsigned short* __restrict__ A, int lda,
    const unsigned short* __restrict__ Bt, int ldb, int K,
    void* __restrict__ outp, int ldo,
    const float* __restrict__ bias, const float* __restrict__ resid) {
  __shared__ unsigned short As[BM * BK];
  __shared__ unsigned short Bs[BN * BK];
  const int t = threadIdx.x;
  const int w = t >> 6, l = t & 63;
  const int wm = w & 1, wn = w >> 1;
  const int q = l >> 4, ln = l & 15;

  const int L = blockIdx.y * 16 + blockIdx.x;
  const int xcd = L & 7;
  const int W = L >> 3;
  const int bx = W & 15;
  const int by = (W >> 4) * 8 + xcd;
  const int m0 = by * BM, n0 = bx * BN;

  f32x4 acc[4][4];
#pragma unroll
  for (int i = 0; i < 4; ++i)
#pragma unroll
    for (int j = 0; j < 4; ++j) acc[i][j] = {0.f, 0.f, 0.f, 0.f};

  for (int k0 = 0; k0 < K; k0 += BK) {
    __syncthreads();
#pragma unroll
    for (int r = 0; r < 4; ++r) {
      int s = r * 256 + t;
      int row = s >> 3;
      int ch = (s & 7) ^ (row & 7);
      const unsigned short* ga = A + (size_t)(m0 + row) * lda + k0 + ch * 8;
      __builtin_amdgcn_global_load_lds(
          (const __attribute__((address_space(1))) void*)ga,
          (__attribute__((address_space(3))) void*)(As + (r * 256 + w * 64) * 8), 16, 0, 0);
      const unsigned short* gb = Bt + (size_t)(n0 + row) * ldb + k0 + ch * 8;
      __builtin_amdgcn_global_load_lds(
          (const __attribute__((address_space(1))) void*)gb,
          (__attribute__((address_space(3))) void*)(Bs + (r * 256 + w * 64) * 8), 16, 0, 0);
    }
    __syncthreads();
#pragma unroll
    for (int h = 0; h < 2; ++h) {
      bf16x8 af[4], bfr[4];
#pragma unroll
      for (int mt = 0; mt < 4; ++mt) {
        int ar = wm * 64 + mt * 16 + ln;
        af[mt] = *(const bf16x8*)&As[ar * BK + (((h * 4 + q) ^ (ar & 7)) * 8)];
      }
#pragma unroll
      for (int nt = 0; nt < 4; ++nt) {
        int br = wn * 64 + nt * 16 + ln;
        bfr[nt] = *(const bf16x8*)&Bs[br * BK + (((h * 4 + q) ^ (br & 7)) * 8)];
      }
#pragma unroll
      for (int mt = 0; mt < 4; ++mt)
#pragma unroll
        for (int nt = 0; nt < 4; ++nt)
          acc[mt][nt] = __builtin_amdgcn_mfma_f32_16x16x32_bf16(af[mt], bfr[nt], acc[mt][nt], 0, 0, 0);
    }
  }

#pragma unroll
  for (int mt = 0; mt < 4; ++mt) {
#pragma unroll
    for (int i = 0; i < 4; ++i) {
      int row = m0 + wm * 64 + mt * 16 + q * 4 + i;
#pragma unroll
      for (int nt = 0; nt < 4; ++nt) {
        int col = n0 + wn * 64 + nt * 16 + ln;
        float vv = acc[mt][nt][i];
        if (MODE == 2) { vv += bias[(size_t)(row >> 11) * 2048 + col]; vv = fmaxf(vv, 0.f); }
        if (MODE == 4) {
          vv += bias[col]; vv = fmaxf(vv, 0.f);
          vv += resid[(size_t)row * 2048 + col];
          ((float*)outp)[(size_t)row * ldo + col] = vv;
        } else {
          ((unsigned short*)outp)[(size_t)row * ldo + col] = f2bf(vv);
        }
      }
    }
  }
}

// ============================================================================
// 256x256 8-phase GEMM (R1-VERIFIED schedule, restored in R5).
// Session A/B evidence: this exact schedule with vmcnt(8) = 127.5us / 47%
// MfmaUtil; two variants with vmcnt(6) (R2 read-ahead, R4 balanced reads)
// both ~34-36% -- the counted-6 wait forces 2 extra load retirements on the
// critical path each half-tile. DO NOT tighten vmcnt below 8 here.
//   C[M,N] = A[M,K](bf16,lda) * Bt[N,K](bf16,ldb)^T
//   grid = (N/256, M/256), 512 threads (8 waves, 2M x 4N), 128 KiB LDS.
// Phase layout per K-tile tt (buf c = tt&1), 16 MFMA each:
//   P1: rd A(kh0) 8x + B(kh0,nt01) 2x | stage A(t+1,kh1)->c^1 | MM
//   P2: rd B(kh0,nt23) 2x             | stage B(t+1,kh1)->c^1 | MM  vmcnt(8)
//   P3: rd A(kh1) 8x + B(kh1,nt01)    | stage A(t+2,kh0)->c   | MM
//   P4: rd B(kh1,nt23)                | stage B(t+2,kh0)->c   | MM  vmcnt(8)
// ============================================================================
#define GLD16(g, s)                                                        \
  __builtin_amdgcn_global_load_lds(                                        \
      (const __attribute__((address_space(1))) void*)(g),                  \
      (__attribute__((address_space(3))) void*)(s), 16, 0, 0)
#define BARX() asm volatile("s_barrier" ::: "memory")
#define VMW8() asm volatile("s_waitcnt vmcnt(8)" ::: "memory")
#define VMW4() asm volatile("s_waitcnt vmcnt(4)" ::: "memory")
#define VMW0() asm volatile("s_waitcnt vmcnt(0)" ::: "memory")

template <int MODE>
__global__ __launch_bounds__(512, 2) void gemm256_kernel(
    const unsigned short* __restrict__ A, int lda,
    const unsigned short* __restrict__ Bt, int ldb, int K,
    void* __restrict__ outp, int ldo,
    const float* __restrict__ bias, const float* __restrict__ resid) {
  __shared__ unsigned short As[2][2][256 * 32];
  __shared__ unsigned short Bs[2][2][256 * 32];
  const int t = threadIdx.x;
  const int wv = t >> 6, l = t & 63;
  const int wm = wv >> 2, wn = wv & 3;   // 2 x 4 wave grid
  const int q = l >> 4, ln = l & 15;

  // XCD-aware swizzle: 256 blocks -> each XCD owns a contiguous 4x8 band.
  const int L = blockIdx.y * 8 + blockIdx.x;
  const int lin = (L & 7) * 32 + (L >> 3);
  const int m0 = (lin >> 3) * 256, n0 = (lin & 7) * 256;

  // staging coords (identical for both 128-row rounds of a half-tile)
  const int srow = t >> 2;                                    // 0..127
  const int scol = (((t & 3) * 16) ^ (((srow >> 1) & 3) << 4)) >> 1;  // elems
  const unsigned short* Abase = A + (size_t)(m0 + srow) * lda + scol;
  const unsigned short* Bbase = Bt + (size_t)(n0 + srow) * ldb + scol;
  const size_t astep = (size_t)128 * lda, bstep = (size_t)128 * ldb;
  const int rsel = (q * 8) ^ (((ln >> 1) & 3) << 3);  // read swizzle (elems)

  f32x4 acc[8][4];
#pragma unroll
  for (int i = 0; i < 8; ++i)
#pragma unroll
    for (int j = 0; j < 4; ++j) acc[i][j] = {0.f, 0.f, 0.f, 0.f};

  auto stageA = [&](int kt, int kh, int buf) {
    const unsigned short* g = Abase + (size_t)kt * 64 + kh * 32;
    GLD16(g, &As[buf][kh][wv * 512]);
    GLD16(g + astep, &As[buf][kh][4096 + wv * 512]);
  };
  auto stageB = [&](int kt, int kh, int buf) {
    const unsigned short* g = Bbase + (size_t)kt * 64 + kh * 32;
    GLD16(g, &Bs[buf][kh][wv * 512]);
    GLD16(g + bstep, &Bs[buf][kh][4096 + wv * 512]);
  };

  bf16x8 a[8], b[2];
  auto loadA = [&](int buf, int h) {
#pragma unroll
    for (int mt = 0; mt < 8; ++mt) {
      int ar = wm * 128 + mt * 16 + ln;
      a[mt] = *(const bf16x8*)&As[buf][h][ar * 32 + rsel];
    }
  };
  auto loadB2 = [&](int buf, int h, int np) {
#pragma unroll
    for (int i = 0; i < 2; ++i) {
      int br = wn * 64 + (np * 2 + i) * 16 + ln;
      b[i] = *(const bf16x8*)&Bs[buf][h][br * 32 + rsel];
    }
  };
  auto mm = [&](int np) {
    __builtin_amdgcn_s_setprio(1);
#pragma unroll
    for (int mt = 0; mt < 8; ++mt)
#pragma unroll
      for (int i = 0; i < 2; ++i)
        acc[mt][np * 2 + i] =
            __builtin_amdgcn_mfma_f32_16x16x32_bf16(a[mt], b[i], acc[mt][np * 2 + i], 0, 0, 0);
    __builtin_amdgcn_s_setprio(0);
  };

  const int NT = K >> 6;
  // prologue: tile0 full + tile1 kh0  (6 half-tiles, 12 loads)
  stageA(0, 0, 0); stageB(0, 0, 0);
  stageA(0, 1, 0); stageB(0, 1, 0);
  stageA(1, 0, 1); stageB(1, 0, 1);
  VMW4();   // oldest retired = tile0 kh0 (A+B)
  BARX();

  for (int tt = 0; tt < NT; ++tt) {
    const int c = tt & 1;
    const int t1 = (tt + 1 == NT) ? 0 : tt + 1;          // wrap: harmless re-stage
    const int t2 = (tt + 2 >= NT) ? tt + 2 - NT : tt + 2;
    // ---- phase 1: kh0, nt{0,1} ----
    loadA(c, 0); loadB2(c, 0, 0);
    stageA(t1, 1, c ^ 1);
    BARX();
    mm(0);
    BARX();
    // ---- phase 2: kh0, nt{2,3} ----
    loadB2(c, 0, 1);
    stageB(t1, 1, c ^ 1);
    BARX();
    mm(1);
    VMW8();
    BARX();
    // ---- phase 3: kh1, nt{0,1} ----
    loadA(c, 1); loadB2(c, 1, 0);
    stageA(t2, 0, c);
    BARX();
    mm(0);
    BARX();
    // ---- phase 4: kh1, nt{2,3} ----
    loadB2(c, 1, 1);
    stageB(t2, 0, c);
    BARX();
    mm(1);
    VMW8();
    BARX();
  }
  VMW0();   // drain trailing (wrapped) stages before epilogue / endpgm

#pragma unroll
  for (int mt = 0; mt < 8; ++mt) {
#pragma unroll
    for (int i = 0; i < 4; ++i) {
      int row = m0 + wm * 128 + mt * 16 + q * 4 + i;
#pragma unroll
      for (int nt = 0; nt < 4; ++nt) {
        int col = n0 + wn * 64 + nt * 16 + ln;
        float vv = acc[mt][nt][i];
        if (MODE == 2) { vv += bias[(size_t)(row >> 11) * 2048 + col]; vv = fmaxf(vv, 0.f); }
        if (MODE == 4) {
          vv += bias[col]; vv = fmaxf(vv, 0.f);
          vv += resid[(size_t)row * 2048 + col];
          ((float*)outp)[(size_t)row * ldo + col] = vv;
        } else {
          ((unsigned short*)outp)[(size_t)row * ldo + col] = f2bf(vv);
        }
      }
    }
  }
}

// ---- chunked scan over S of v[b][s][c] ----
__global__ __launch_bounds__(256) void scan_partial_kernel(
    const unsigned short* __restrict__ v, float* __restrict__ csum) {
  int c = blockIdx.x * 256 + threadIdx.x;
  int chunk = blockIdx.y, b = blockIdx.z;
  const unsigned short* p = v + ((size_t)(b * S_DIM + chunk * CHLEN)) * D_DIM + c;
  float s = 0.f;
#pragma unroll 4
  for (int i = 0; i < CHLEN; ++i) s += bf2f(p[(size_t)i * D_DIM]);
  csum[((size_t)b * NCHUNK + chunk) * D_DIM + c] = s;
}

// writes pooled directly into concat[:, 2048:4096] (ld 4096).
// Computes its own chunk-prefix from csum partials (scan_offsets removed).
__global__ __launch_bounds__(256) void scan_apply_kernel(
    const unsigned short* __restrict__ v, const float* __restrict__ csum,
    const float* __restrict__ coef, unsigned short* __restrict__ pooled_out) {
  int c = blockIdx.x * 256 + threadIdx.x;
  int chunk = blockIdx.y, b = blockIdx.z;
  int h = c >> 7;
  int row0 = b * S_DIM + chunk * CHLEN;
  const float* cs = csum + (size_t)b * NCHUNK * D_DIM + c;
  float run = 0.f;
  for (int j = 0; j < chunk; ++j) run += cs[(size_t)j * D_DIM];
  const unsigned short* vp = v + (size_t)row0 * D_DIM + c;
  unsigned short* po = pooled_out + (size_t)row0 * CONCAT_LD + c;
  const float* cf = coef + (size_t)row0 * H_DIM + h;
#pragma unroll 4
  for (int i = 0; i < CHLEN; ++i) {
    run += bf2f(vp[(size_t)i * D_DIM]);
    po[(size_t)i * CONCAT_LD] = f2bf(cf[(size_t)i * H_DIM] * run);
  }
}

// ---- in-place LayerNorm on d_out rows ----
__global__ __launch_bounds__(256) void ln_kernel(
    float* __restrict__ out, const float* __restrict__ gamma, const float* __restrict__ beta) {
  int row = blockIdx.x, t = threadIdx.x;
  float* pr = out + (size_t)row * D_DIM;
  float vals[8];
  float s = 0.f;
#pragma unroll
  for (int i = 0; i < 8; ++i) { vals[i] = pr[t + i * 256]; s += vals[i]; }
  __shared__ float red[4];
  for (int off = 32; off; off >>= 1) s += __shfl_down(s, off);
  if ((t & 63) == 0) red[t >> 6] = s;
  __syncthreads();
  float mean = (red[0] + red[1] + red[2] + red[3]) * (1.f / D_DIM);
  __syncthreads();
  float c2 = 0.f;
#pragma unroll
  for (int i = 0; i < 8; ++i) { float c = vals[i] - mean; c2 += c * c; }
  for (int off = 32; off; off >>= 1) c2 += __shfl_down(c2, off);
  if ((t & 63) == 0) red[t >> 6] = c2;
  __syncthreads();
  float var = (red[0] + red[1] + red[2] + red[3]) * (1.f / D_DIM);
  float rstd = rsqrtf(var + 1e-6f);
#pragma unroll
  for (int i = 0; i < 8; ++i) {
    int col = t + i * 256;
    pr[col] = (vals[i] - mean) * rstd * gamma[col] + beta[col];
  }
}

extern "C" void kernel_launch(void* const* d_in, const int* in_sizes, int n_in,
                              void* d_out, int out_size, void* d_ws, size_t ws_size,
                              hipStream_t stream) {
  const float* x      = (const float*)d_in[0];
  const float* vector = (const float*)d_in[1];
  const float* W_att  = (const float*)d_in[2];
  const float* temp   = (const float*)d_in[3];
  const float* W_val  = (const float*)d_in[4];
  const float* W_op   = (const float*)d_in[5];
  const float* ff1    = (const float*)d_in[6];
  const float* ff1_b  = (const float*)d_in[7];
  const float* ff2    = (const float*)d_in[8];
  const float* ff2_b  = (const float*)d_in[9];
  const float* gamma  = (const float*)d_in[10];
  const float* beta   = (const float*)d_in[11];
  float* out = (float*)d_out;

  char* ws = (char*)d_ws;
  auto alloc = [&](size_t bytes) {
    char* p = ws; ws += (bytes + 255) & ~(size_t)255; return p;
  };
  unsigned short* concat = (unsigned short*)alloc((size_t)M_ROWS * CONCAT_LD * 2);  // [x | pooled]
  unsigned short* wv_t   = (unsigned short*)alloc((size_t)2048 * 2048 * 2);
  unsigned short* btff1  = (unsigned short*)alloc((size_t)2048 * 4096 * 2);  // [F1a^T | Wc^T] rows n, ld 4096
  unsigned short* f1bT   = (unsigned short*)alloc((size_t)2048 * 2048 * 2);
  unsigned short* wop_bf = (unsigned short*)alloc((size_t)2048 * 2048 * 2);
  unsigned short* ff2_t  = (unsigned short*)alloc((size_t)2048 * 2048 * 2);
  unsigned short* vbuf   = (unsigned short*)alloc((size_t)M_ROWS * 2048 * 2);
  unsigned short* h1     = (unsigned short*)alloc((size_t)M_ROWS * 2048 * 2);
  float* logits = (float*)alloc((size_t)M_ROWS * H_DIM * 4);
  float* coef   = (float*)alloc((size_t)M_ROWS * H_DIM * 4);
  float* csum   = (float*)alloc((size_t)B_DIM * NCHUNK * D_DIM * 4);
  float* part   = (float*)alloc((size_t)16 * 4 * 2048 * 4);
  float* bias2  = (float*)alloc((size_t)4 * 2048 * 4);

  prep_kernel<<<dim3(64, 64, 5), 256, 0, stream>>>(
      W_val, ff1, ff2, W_op, wv_t, btff1, f1bT, ff2_t, wop_bf);
  xconv_logits_kernel<<<M_ROWS, 256, 0, stream>>>(x, W_att, concat, logits);
  coef_kernel<<<B_DIM * H_DIM, 256, 0, stream>>>(logits, temp, coef);
  // Wc^T[n][i] = (F1b^T @ W_op^T)[n][i] -> btff1[:, 2048:4096]  (small: keep 128^2)
  gemm_bt_kernel<1><<<dim3(16, 16), 256, 0, stream>>>(
      f1bT, 2048, wop_bf, 2048, 2048, btff1 + 2048, 4096, nullptr, nullptr);
  // bias2 = vector @ F1b + ff1_b
  bias2_partial_kernel<<<dim3(8, 16, 4), 256, 0, stream>>>(vector, ff1, part);
  bias2_reduce_kernel<<<dim3(8, 4), 256, 0, stream>>>(part, ff1_b, bias2);
  // v = x @ W_values   (256^2, R1 schedule)
  gemm256_kernel<1><<<dim3(8, 32), 512, 0, stream>>>(
      concat, CONCAT_LD, wv_t, 2048, 2048, vbuf, 2048, nullptr, nullptr);
  scan_partial_kernel<<<dim3(8, NCHUNK, B_DIM), 256, 0, stream>>>(vbuf, csum);
  scan_apply_kernel<<<dim3(8, NCHUNK, B_DIM), 256, 0, stream>>>(vbuf, csum, coef, concat + 2048);
  // h1 = relu([x|pooled] @ [F1a;Wc] + bias2[b])   (256^2, R1 schedule, K=4096)
  gemm256_kernel<2><<<dim3(8, 32), 512, 0, stream>>>(
      concat, CONCAT_LD, btff1, 4096, 4096, h1, 2048, bias2, nullptr);
  // out = relu(h1 @ ff2 + ff2_b) + x   (256^2, R1 schedule)
  gemm256_kernel<4><<<dim3(8, 32), 512, 0, stream>>>(
      h1, 2048, ff2_t, 2048, 2048, out, 2048, ff2_b, x);
  ln_kernel<<<M_ROWS, 256, 0, stream>>>(out, gamma, beta);
}

// Round 6
// 627.587 us; speedup vs baseline: 1.1447x; 1.0380x over previous
//
#include <hip/hip_runtime.h>
#include <stdint.h>

#define B_DIM 4
#define S_DIM 2048
#define D_DIM 2048
#define H_DIM 16
#define M_ROWS (B_DIM * S_DIM)   // 8192
#define CONCAT_LD 4096
#define NCHUNK 64
#define CHLEN (S_DIM / NCHUNK)   // 32

#define BM 128
#define BN 128
#define BK 64

typedef __attribute__((ext_vector_type(8))) __bf16 bf16x8;
typedef __attribute__((ext_vector_type(4))) float f32x4;

__device__ inline unsigned short f2bf(float f) {
  union { float f; unsigned u; } x; x.f = f;
  unsigned r = x.u + 0x7fffu + ((x.u >> 16) & 1u);
  return (unsigned short)(r >> 16);
}
__device__ inline float bf2f(unsigned short s) {
  union { unsigned u; float f; } x; x.u = ((unsigned)s) << 16;
  return x.f;
}
__device__ inline float bfLo(unsigned u) {
  union { unsigned x; float f; } c; c.x = u << 16; return c.f;
}
__device__ inline float bfHi(unsigned u) {
  union { unsigned x; float f; } c; c.x = u & 0xffff0000u; return c.f;
}

// ---- fused: x fp32 -> bf16 into concat[:,0:2048] AND logits = x @ W_att ----
// R6: 4 rows/block (W_att L2 traffic /4), float4 x loads, ushort4 stores.
__global__ __launch_bounds__(256) void xconv_logits_kernel(
    const float* __restrict__ x, const float* __restrict__ Watt,
    unsigned short* __restrict__ concat, float* __restrict__ logits) {
  int r0 = blockIdx.x * 4, t = threadIdx.x;
  float p[4][H_DIM];
#pragma unroll
  for (int r = 0; r < 4; ++r)
#pragma unroll
    for (int h = 0; h < H_DIM; ++h) p[r][h] = 0.f;
#pragma unroll
  for (int i = 0; i < 2; ++i) {
    int k = t * 4 + i * 1024;
    float4 xv[4];
#pragma unroll
    for (int r = 0; r < 4; ++r) {
      xv[r] = *(const float4*)(x + (size_t)(r0 + r) * D_DIM + k);
      ushort4 o;
      o.x = f2bf(xv[r].x); o.y = f2bf(xv[r].y); o.z = f2bf(xv[r].z); o.w = f2bf(xv[r].w);
      *(ushort4*)(concat + (size_t)(r0 + r) * CONCAT_LD + k) = o;
    }
#pragma unroll
    for (int kk = 0; kk < 4; ++kk) {
      const float* w = Watt + (size_t)(k + kk) * H_DIM;
      float wr[H_DIM];
#pragma unroll
      for (int h = 0; h < H_DIM; ++h) wr[h] = w[h];
#pragma unroll
      for (int r = 0; r < 4; ++r) {
        float xs = (kk == 0) ? xv[r].x : (kk == 1) ? xv[r].y : (kk == 2) ? xv[r].z : xv[r].w;
#pragma unroll
        for (int h = 0; h < H_DIM; ++h) p[r][h] += xs * wr[h];
      }
    }
  }
  __shared__ float red[4][4][H_DIM];
  int l = t & 63, w = t >> 6;
#pragma unroll
  for (int r = 0; r < 4; ++r)
#pragma unroll
    for (int h = 0; h < H_DIM; ++h) {
      float v = p[r][h];
      for (int off = 32; off; off >>= 1) v += __shfl_down(v, off);
      if (l == 0) red[w][r][h] = v;
    }
  __syncthreads();
  if (t < 64) {
    int r = t >> 4, h = t & 15;
    logits[(size_t)(r0 + r) * H_DIM + h] =
        red[0][r][h] + red[1][r][h] + red[2][r][h] + red[3][r][h];
  }
}

// ---- fused weight prep: 4 transposes (fp32->bf16^T, 64x32 tiles, ushort2
// writes) + 1 convert.  grid (64, 32, 5). ----
__global__ __launch_bounds__(256) void prep_kernel(
    const float* __restrict__ Wval, const float* __restrict__ ff1,
    const float* __restrict__ ff2, const float* __restrict__ Wop,
    unsigned short* __restrict__ wv_t, unsigned short* __restrict__ btff1,
    unsigned short* __restrict__ f1bT, unsigned short* __restrict__ ff2_t,
    unsigned short* __restrict__ wop_bf) {
  int z = blockIdx.z, t = threadIdx.x;
  if (z == 4) {
    size_t idx = (((size_t)blockIdx.y * 64 + blockIdx.x) * 256 + t) * 8;
    const float4 v0 = *(const float4*)(Wop + idx);
    const float4 v1 = *(const float4*)(Wop + idx + 4);
    ushort4 a, b;
    a.x = f2bf(v0.x); a.y = f2bf(v0.y); a.z = f2bf(v0.z); a.w = f2bf(v0.w);
    b.x = f2bf(v1.x); b.y = f2bf(v1.y); b.z = f2bf(v1.z); b.w = f2bf(v1.w);
    *(ushort4*)(wop_bf + idx) = a;
    *(ushort4*)(wop_bf + idx + 4) = b;
    return;
  }
  const float* src;
  unsigned short* dst;
  int ldd;
  if (z == 0)      { src = Wval;                        dst = wv_t;  ldd = 2048; }
  else if (z == 1) { src = ff1;                         dst = btff1; ldd = 4096; }
  else if (z == 2) { src = ff1 + (size_t)2048 * 2048;   dst = f1bT;  ldd = 2048; }
  else             { src = ff2;                         dst = ff2_t; ldd = 2048; }
  __shared__ float tile[64][33];
  int c0 = blockIdx.x * 32, r0 = blockIdx.y * 64;
  int tx = t & 31, ty = t >> 5;
#pragma unroll
  for (int i = 0; i < 64; i += 8)
    tile[ty + i][tx] = src[(size_t)(r0 + ty + i) * 2048 + c0 + tx];
  __syncthreads();
  int sx = t & 31, sy = t >> 5;
#pragma unroll
  for (int j = 0; j < 32; j += 8) {
    int c = c0 + sy + j;
    ushort2 o;
    o.x = f2bf(tile[sx * 2][sy + j]);
    o.y = f2bf(tile[sx * 2 + 1][sy + j]);
    *(ushort2*)(dst + (size_t)c * ldd + r0 + sx * 2) = o;
  }
}

// ---- per (b,h): max over s, then coef = w/(w*(s+1)+1e-30), w=exp((lg-mx)*T) ----
__global__ __launch_bounds__(256) void coef_kernel(
    const float* __restrict__ logits, const float* __restrict__ temp, float* __restrict__ coef) {
  int b = blockIdx.x >> 4, h = blockIdx.x & 15;
  int t = threadIdx.x;
  const float* lg = logits + (size_t)b * S_DIM * H_DIM + h;
  float mx = -1e30f;
  for (int s = t; s < S_DIM; s += 256) mx = fmaxf(mx, lg[(size_t)s * H_DIM]);
  for (int off = 32; off; off >>= 1) mx = fmaxf(mx, __shfl_down(mx, off));
  __shared__ float red[4];
  if ((t & 63) == 0) red[t >> 6] = mx;
  __syncthreads();
  mx = fmaxf(fmaxf(red[0], red[1]), fmaxf(red[2], red[3]));
  float T = temp[h];
  float* cf = coef + (size_t)b * S_DIM * H_DIM + h;
  for (int s = t; s < S_DIM; s += 256) {
    float w = expf((lg[(size_t)s * H_DIM] - mx) * T);
    cf[(size_t)s * H_DIM] = w / (w * (float)(s + 1) + 1e-30f);
  }
}

// ---- bias2 = vector @ F1b (+ ff1_b), partial over j-segments then reduce ----
__global__ __launch_bounds__(256) void bias2_partial_kernel(
    const float* __restrict__ vector, const float* __restrict__ ff1,
    float* __restrict__ part) {
  int n = blockIdx.x * 256 + threadIdx.x;
  int seg = blockIdx.y, b = blockIdx.z;
  const float* vr = vector + (size_t)b * 2048 + seg * 128;
  const float* fr = ff1 + (size_t)(2048 + seg * 128) * 2048 + n;
  float acc = 0.f;
#pragma unroll 8
  for (int j = 0; j < 128; ++j) acc += vr[j] * fr[(size_t)j * 2048];
  part[((size_t)seg * 4 + b) * 2048 + n] = acc;
}

__global__ __launch_bounds__(256) void bias2_reduce_kernel(
    const float* __restrict__ part, const float* __restrict__ ff1_b,
    float* __restrict__ bias2) {
  int n = blockIdx.x * 256 + threadIdx.x;
  int b = blockIdx.y;
  float acc = ff1_b[n];
#pragma unroll
  for (int s = 0; s < 16; ++s) acc += part[((size_t)s * 4 + b) * 2048 + n];
  bias2[(size_t)b * 2048 + n] = acc;
}

// ---- 128x128 GEMM (m97 structure) -- kept for the small 2048^3 Wc GEMM ----
template <int MODE>
__global__ __launch_bounds__(256) void gemm_bt_kernel(
    const unsigned short* __restrict__ A, int lda,
    const unsigned short* __restrict__ Bt, int ldb, int K,
    void* __restrict__ outp, int ldo,
    const float* __restrict__ bias, const float* __restrict__ resid) {
  __shared__ unsigned short As[BM * BK];
  __shared__ unsigned short Bs[BN * BK];
  const int t = threadIdx.x;
  const int w = t >> 6, l = t & 63;
  const int wm = w & 1, wn = w >> 1;
  const int q = l >> 4, ln = l & 15;

  const int L = blockIdx.y * 16 + blockIdx.x;
  const int xcd = L & 7;
  const int W = L >> 3;
  const int bx = W & 15;
  const int by = (W >> 4) * 8 + xcd;
  const int m0 = by * BM, n0 = bx * BN;

  f32x4 acc[4][4];
#pragma unroll
  for (int i = 0; i < 4; ++i)
#pragma unroll
    for (int j = 0; j < 4; ++j) acc[i][j] = {0.f, 0.f, 0.f, 0.f};

  for (int k0 = 0; k0 < K; k0 += BK) {
    __syncthreads();
#pragma unroll
    for (int r = 0; r < 4; ++r) {
      int s = r * 256 + t;
      int row = s >> 3;
      int ch = (s & 7) ^ (row & 7);
      const unsigned short* ga = A + (size_t)(m0 + row) * lda + k0 + ch * 8;
      __builtin_amdgcn_global_load_lds(
          (const __attribute__((address_space(1))) void*)ga,
          (__attribute__((address_space(3))) void*)(As + (r * 256 + w * 64) * 8), 16, 0, 0);
      const unsigned short* gb = Bt + (size_t)(n0 + row) * ldb + k0 + ch * 8;
      __builtin_amdgcn_global_load_lds(
          (const __attribute__((address_space(1))) void*)gb,
          (__attribute__((address_space(3))) void*)(Bs + (r * 256 + w * 64) * 8), 16, 0, 0);
    }
    __syncthreads();
#pragma unroll
    for (int h = 0; h < 2; ++h) {
      bf16x8 af[4], bfr[4];
#pragma unroll
      for (int mt = 0; mt < 4; ++mt) {
        int ar = wm * 64 + mt * 16 + ln;
        af[mt] = *(const bf16x8*)&As[ar * BK + (((h * 4 + q) ^ (ar & 7)) * 8)];
      }
#pragma unroll
      for (int nt = 0; nt < 4; ++nt) {
        int br = wn * 64 + nt * 16 + ln;
        bfr[nt] = *(const bf16x8*)&Bs[br * BK + (((h * 4 + q) ^ (br & 7)) * 8)];
      }
#pragma unroll
      for (int mt = 0; mt < 4; ++mt)
#pragma unroll
        for (int nt = 0; nt < 4; ++nt)
          acc[mt][nt] = __builtin_amdgcn_mfma_f32_16x16x32_bf16(af[mt], bfr[nt], acc[mt][nt], 0, 0, 0);
    }
  }

#pragma unroll
  for (int mt = 0; mt < 4; ++mt) {
#pragma unroll
    for (int i = 0; i < 4; ++i) {
      int row = m0 + wm * 64 + mt * 16 + q * 4 + i;
#pragma unroll
      for (int nt = 0; nt < 4; ++nt) {
        int col = n0 + wn * 64 + nt * 16 + ln;
        float vv = acc[mt][nt][i];
        if (MODE == 2) { vv += bias[(size_t)(row >> 11) * 2048 + col]; vv = fmaxf(vv, 0.f); }
        if (MODE == 4) {
          vv += bias[col]; vv = fmaxf(vv, 0.f);
          vv += resid[(size_t)row * 2048 + col];
          ((float*)outp)[(size_t)row * ldo + col] = vv;
        } else {
          ((unsigned short*)outp)[(size_t)row * ldo + col] = f2bf(vv);
        }
      }
    }
  }
}

// ============================================================================
// 256x256 8-phase GEMM (R1/R5-VERIFIED schedule -- DO NOT MODIFY).
// A/B evidence: this schedule with vmcnt(8) = 127.5us / 46-47% MfmaUtil;
// vmcnt(6) variants (R2 read-ahead, R4 balanced) both regressed to 34-36%.
// ============================================================================
#define GLD16(g, s)                                                        \
  __builtin_amdgcn_global_load_lds(                                        \
      (const __attribute__((address_space(1))) void*)(g),                  \
      (__attribute__((address_space(3))) void*)(s), 16, 0, 0)
#define BARX() asm volatile("s_barrier" ::: "memory")
#define VMW8() asm volatile("s_waitcnt vmcnt(8)" ::: "memory")
#define VMW4() asm volatile("s_waitcnt vmcnt(4)" ::: "memory")
#define VMW0() asm volatile("s_waitcnt vmcnt(0)" ::: "memory")

template <int MODE>
__global__ __launch_bounds__(512, 2) void gemm256_kernel(
    const unsigned short* __restrict__ A, int lda,
    const unsigned short* __restrict__ Bt, int ldb, int K,
    void* __restrict__ outp, int ldo,
    const float* __restrict__ bias, const float* __restrict__ resid) {
  __shared__ unsigned short As[2][2][256 * 32];
  __shared__ unsigned short Bs[2][2][256 * 32];
  const int t = threadIdx.x;
  const int wv = t >> 6, l = t & 63;
  const int wm = wv >> 2, wn = wv & 3;   // 2 x 4 wave grid
  const int q = l >> 4, ln = l & 15;

  const int L = blockIdx.y * 8 + blockIdx.x;
  const int lin = (L & 7) * 32 + (L >> 3);
  const int m0 = (lin >> 3) * 256, n0 = (lin & 7) * 256;

  const int srow = t >> 2;                                    // 0..127
  const int scol = (((t & 3) * 16) ^ (((srow >> 1) & 3) << 4)) >> 1;  // elems
  const unsigned short* Abase = A + (size_t)(m0 + srow) * lda + scol;
  const unsigned short* Bbase = Bt + (size_t)(n0 + srow) * ldb + scol;
  const size_t astep = (size_t)128 * lda, bstep = (size_t)128 * ldb;
  const int rsel = (q * 8) ^ (((ln >> 1) & 3) << 3);  // read swizzle (elems)

  f32x4 acc[8][4];
#pragma unroll
  for (int i = 0; i < 8; ++i)
#pragma unroll
    for (int j = 0; j < 4; ++j) acc[i][j] = {0.f, 0.f, 0.f, 0.f};

  auto stageA = [&](int kt, int kh, int buf) {
    const unsigned short* g = Abase + (size_t)kt * 64 + kh * 32;
    GLD16(g, &As[buf][kh][wv * 512]);
    GLD16(g + astep, &As[buf][kh][4096 + wv * 512]);
  };
  auto stageB = [&](int kt, int kh, int buf) {
    const unsigned short* g = Bbase + (size_t)kt * 64 + kh * 32;
    GLD16(g, &Bs[buf][kh][wv * 512]);
    GLD16(g + bstep, &Bs[buf][kh][4096 + wv * 512]);
  };

  bf16x8 a[8], b[2];
  auto loadA = [&](int buf, int h) {
#pragma unroll
    for (int mt = 0; mt < 8; ++mt) {
      int ar = wm * 128 + mt * 16 + ln;
      a[mt] = *(const bf16x8*)&As[buf][h][ar * 32 + rsel];
    }
  };
  auto loadB2 = [&](int buf, int h, int np) {
#pragma unroll
    for (int i = 0; i < 2; ++i) {
      int br = wn * 64 + (np * 2 + i) * 16 + ln;
      b[i] = *(const bf16x8*)&Bs[buf][h][br * 32 + rsel];
    }
  };
  auto mm = [&](int np) {
    __builtin_amdgcn_s_setprio(1);
#pragma unroll
    for (int mt = 0; mt < 8; ++mt)
#pragma unroll
      for (int i = 0; i < 2; ++i)
        acc[mt][np * 2 + i] =
            __builtin_amdgcn_mfma_f32_16x16x32_bf16(a[mt], b[i], acc[mt][np * 2 + i], 0, 0, 0);
    __builtin_amdgcn_s_setprio(0);
  };

  const int NT = K >> 6;
  stageA(0, 0, 0); stageB(0, 0, 0);
  stageA(0, 1, 0); stageB(0, 1, 0);
  stageA(1, 0, 1); stageB(1, 0, 1);
  VMW4();
  BARX();

  for (int tt = 0; tt < NT; ++tt) {
    const int c = tt & 1;
    const int t1 = (tt + 1 == NT) ? 0 : tt + 1;
    const int t2 = (tt + 2 >= NT) ? tt + 2 - NT : tt + 2;
    // ---- phase 1: kh0, nt{0,1} ----
    loadA(c, 0); loadB2(c, 0, 0);
    stageA(t1, 1, c ^ 1);
    BARX();
    mm(0);
    BARX();
    // ---- phase 2: kh0, nt{2,3} ----
    loadB2(c, 0, 1);
    stageB(t1, 1, c ^ 1);
    BARX();
    mm(1);
    VMW8();
    BARX();
    // ---- phase 3: kh1, nt{0,1} ----
    loadA(c, 1); loadB2(c, 1, 0);
    stageA(t2, 0, c);
    BARX();
    mm(0);
    BARX();
    // ---- phase 4: kh1, nt{2,3} ----
    loadB2(c, 1, 1);
    stageB(t2, 0, c);
    BARX();
    mm(1);
    VMW8();
    BARX();
  }
  VMW0();

#pragma unroll
  for (int mt = 0; mt < 8; ++mt) {
#pragma unroll
    for (int i = 0; i < 4; ++i) {
      int row = m0 + wm * 128 + mt * 16 + q * 4 + i;
#pragma unroll
      for (int nt = 0; nt < 4; ++nt) {
        int col = n0 + wn * 64 + nt * 16 + ln;
        float vv = acc[mt][nt][i];
        if (MODE == 2) { vv += bias[(size_t)(row >> 11) * 2048 + col]; vv = fmaxf(vv, 0.f); }
        if (MODE == 4) {
          vv += bias[col]; vv = fmaxf(vv, 0.f);
          vv += resid[(size_t)row * 2048 + col];
          ((float*)outp)[(size_t)row * ldo + col] = vv;
        } else {
          ((unsigned short*)outp)[(size_t)row * ldo + col] = f2bf(vv);
        }
      }
    }
  }
}

// ---- chunked scan over S of v[b][s][c] -- vectorized uint4 (8 bf16/lane) ----
__global__ __launch_bounds__(256) void scan_partial_kernel(
    const unsigned short* __restrict__ v, float* __restrict__ csum) {
  int chunk = blockIdx.x, b = blockIdx.y;
  int c0 = threadIdx.x * 8;
  const unsigned short* p = v + ((size_t)(b * S_DIM + chunk * CHLEN)) * D_DIM + c0;
  float s[8];
#pragma unroll
  for (int j = 0; j < 8; ++j) s[j] = 0.f;
  for (int i = 0; i < CHLEN; ++i) {
    uint4 u = *(const uint4*)(p + (size_t)i * D_DIM);
    s[0] += bfLo(u.x); s[1] += bfHi(u.x);
    s[2] += bfLo(u.y); s[3] += bfHi(u.y);
    s[4] += bfLo(u.z); s[5] += bfHi(u.z);
    s[6] += bfLo(u.w); s[7] += bfHi(u.w);
  }
  float* cs = csum + ((size_t)b * NCHUNK + chunk) * D_DIM + c0;
  float4 o0 = {s[0], s[1], s[2], s[3]}, o1 = {s[4], s[5], s[6], s[7]};
  *(float4*)cs = o0;
  *(float4*)(cs + 4) = o1;
}

// pooled into concat[:, 2048:4096]; own chunk-prefix from csum partials.
__global__ __launch_bounds__(256) void scan_apply_kernel(
    const unsigned short* __restrict__ v, const float* __restrict__ csum,
    const float* __restrict__ coef, unsigned short* __restrict__ pooled_out) {
  int chunk = blockIdx.x, b = blockIdx.y;
  int c0 = threadIdx.x * 8;
  const float* cs = csum + (size_t)b * NCHUNK * D_DIM + c0;
  float run[8];
#pragma unroll
  for (int j = 0; j < 8; ++j) run[j] = 0.f;
  for (int j = 0; j < chunk; ++j) {
    float4 a = *(const float4*)(cs + (size_t)j * D_DIM);
    float4 d = *(const float4*)(cs + (size_t)j * D_DIM + 4);
    run[0] += a.x; run[1] += a.y; run[2] += a.z; run[3] += a.w;
    run[4] += d.x; run[5] += d.y; run[6] += d.z; run[7] += d.w;
  }
  int row0 = b * S_DIM + chunk * CHLEN;
  const unsigned short* vp = v + (size_t)row0 * D_DIM + c0;
  unsigned short* po = pooled_out + (size_t)row0 * CONCAT_LD + c0;
  const float* cf = coef + (size_t)row0 * H_DIM + (c0 >> 7);
  for (int i = 0; i < CHLEN; ++i) {
    uint4 u = *(const uint4*)(vp + (size_t)i * D_DIM);
    run[0] += bfLo(u.x); run[1] += bfHi(u.x);
    run[2] += bfLo(u.y); run[3] += bfHi(u.y);
    run[4] += bfLo(u.z); run[5] += bfHi(u.z);
    run[6] += bfLo(u.w); run[7] += bfHi(u.w);
    float cv = cf[(size_t)i * H_DIM];
    uint4 o;
    o.x = (unsigned)f2bf(cv * run[0]) | ((unsigned)f2bf(cv * run[1]) << 16);
    o.y = (unsigned)f2bf(cv * run[2]) | ((unsigned)f2bf(cv * run[3]) << 16);
    o.z = (unsigned)f2bf(cv * run[4]) | ((unsigned)f2bf(cv * run[5]) << 16);
    o.w = (unsigned)f2bf(cv * run[6]) | ((unsigned)f2bf(cv * run[7]) << 16);
    *(uint4*)(po + (size_t)i * CONCAT_LD) = o;
  }
}

// ---- in-place LayerNorm on d_out rows (float4 loads/stores) ----
__global__ __launch_bounds__(256) void ln_kernel(
    float* __restrict__ out, const float* __restrict__ gamma, const float* __restrict__ beta) {
  int row = blockIdx.x, t = threadIdx.x;
  float* pr = out + (size_t)row * D_DIM;
  int c = t * 4;
  float4 va = *(const float4*)(pr + c);
  float4 vb = *(const float4*)(pr + c + 1024);
  float s = va.x + va.y + va.z + va.w + vb.x + vb.y + vb.z + vb.w;
  __shared__ float red[4];
  for (int off = 32; off; off >>= 1) s += __shfl_down(s, off);
  if ((t & 63) == 0) red[t >> 6] = s;
  __syncthreads();
  float mean = (red[0] + red[1] + red[2] + red[3]) * (1.f / D_DIM);
  __syncthreads();
  float c2 = 0.f;
  {
    float d;
    d = va.x - mean; c2 += d * d; d = va.y - mean; c2 += d * d;
    d = va.z - mean; c2 += d * d; d = va.w - mean; c2 += d * d;
    d = vb.x - mean; c2 += d * d; d = vb.y - mean; c2 += d * d;
    d = vb.z - mean; c2 += d * d; d = vb.w - mean; c2 += d * d;
  }
  for (int off = 32; off; off >>= 1) c2 += __shfl_down(c2, off);
  if ((t & 63) == 0) red[t >> 6] = c2;
  __syncthreads();
  float var = (red[0] + red[1] + red[2] + red[3]) * (1.f / D_DIM);
  float rstd = rsqrtf(var + 1e-6f);
  float4 ga = *(const float4*)(gamma + c), ba = *(const float4*)(beta + c);
  float4 gb = *(const float4*)(gamma + c + 1024), bb = *(const float4*)(beta + c + 1024);
  float4 oa, ob;
  oa.x = (va.x - mean) * rstd * ga.x + ba.x;
  oa.y = (va.y - mean) * rstd * ga.y + ba.y;
  oa.z = (va.z - mean) * rstd * ga.z + ba.z;
  oa.w = (va.w - mean) * rstd * ga.w + ba.w;
  ob.x = (vb.x - mean) * rstd * gb.x + bb.x;
  ob.y = (vb.y - mean) * rstd * gb.y + bb.y;
  ob.z = (vb.z - mean) * rstd * gb.z + bb.z;
  ob.w = (vb.w - mean) * rstd * gb.w + bb.w;
  *(float4*)(pr + c) = oa;
  *(float4*)(pr + c + 1024) = ob;
}

extern "C" void kernel_launch(void* const* d_in, const int* in_sizes, int n_in,
                              void* d_out, int out_size, void* d_ws, size_t ws_size,
                              hipStream_t stream) {
  const float* x      = (const float*)d_in[0];
  const float* vector = (const float*)d_in[1];
  const float* W_att  = (const float*)d_in[2];
  const float* temp   = (const float*)d_in[3];
  const float* W_val  = (const float*)d_in[4];
  const float* W_op   = (const float*)d_in[5];
  const float* ff1    = (const float*)d_in[6];
  const float* ff1_b  = (const float*)d_in[7];
  const float* ff2    = (const float*)d_in[8];
  const float* ff2_b  = (const float*)d_in[9];
  const float* gamma  = (const float*)d_in[10];
  const float* beta   = (const float*)d_in[11];
  float* out = (float*)d_out;

  char* ws = (char*)d_ws;
  auto alloc = [&](size_t bytes) {
    char* p = ws; ws += (bytes + 255) & ~(size_t)255; return p;
  };
  unsigned short* concat = (unsigned short*)alloc((size_t)M_ROWS * CONCAT_LD * 2);  // [x | pooled]
  unsigned short* wv_t   = (unsigned short*)alloc((size_t)2048 * 2048 * 2);
  unsigned short* btff1  = (unsigned short*)alloc((size_t)2048 * 4096 * 2);  // [F1a^T | Wc^T] rows n, ld 4096
  unsigned short* f1bT   = (unsigned short*)alloc((size_t)2048 * 2048 * 2);
  unsigned short* wop_bf = (unsigned short*)alloc((size_t)2048 * 2048 * 2);
  unsigned short* ff2_t  = (unsigned short*)alloc((size_t)2048 * 2048 * 2);
  unsigned short* vbuf   = (unsigned short*)alloc((size_t)M_ROWS * 2048 * 2);
  unsigned short* h1     = (unsigned short*)alloc((size_t)M_ROWS * 2048 * 2);
  float* logits = (float*)alloc((size_t)M_ROWS * H_DIM * 4);
  float* coef   = (float*)alloc((size_t)M_ROWS * H_DIM * 4);
  float* csum   = (float*)alloc((size_t)B_DIM * NCHUNK * D_DIM * 4);
  float* part   = (float*)alloc((size_t)16 * 4 * 2048 * 4);
  float* bias2  = (float*)alloc((size_t)4 * 2048 * 4);

  prep_kernel<<<dim3(64, 32, 5), 256, 0, stream>>>(
      W_val, ff1, ff2, W_op, wv_t, btff1, f1bT, ff2_t, wop_bf);
  xconv_logits_kernel<<<M_ROWS / 4, 256, 0, stream>>>(x, W_att, concat, logits);
  coef_kernel<<<B_DIM * H_DIM, 256, 0, stream>>>(logits, temp, coef);
  // Wc^T[n][i] = (F1b^T @ W_op^T)[n][i] -> btff1[:, 2048:4096]
  gemm_bt_kernel<1><<<dim3(16, 16), 256, 0, stream>>>(
      f1bT, 2048, wop_bf, 2048, 2048, btff1 + 2048, 4096, nullptr, nullptr);
  // bias2 = vector @ F1b + ff1_b
  bias2_partial_kernel<<<dim3(8, 16, 4), 256, 0, stream>>>(vector, ff1, part);
  bias2_reduce_kernel<<<dim3(8, 4), 256, 0, stream>>>(part, ff1_b, bias2);
  // v = x @ W_values   (256^2, verified schedule)
  gemm256_kernel<1><<<dim3(8, 32), 512, 0, stream>>>(
      concat, CONCAT_LD, wv_t, 2048, 2048, vbuf, 2048, nullptr, nullptr);
  scan_partial_kernel<<<dim3(NCHUNK, B_DIM), 256, 0, stream>>>(vbuf, csum);
  scan_apply_kernel<<<dim3(NCHUNK, B_DIM), 256, 0, stream>>>(vbuf, csum, coef, concat + 2048);
  // h1 = relu([x|pooled] @ [F1a;Wc] + bias2[b])   (K=4096)
  gemm256_kernel<2><<<dim3(8, 32), 512, 0, stream>>>(
      concat, CONCAT_LD, btff1, 4096, 4096, h1, 2048, bias2, nullptr);
  // out = relu(h1 @ ff2 + ff2_b) + x
  gemm256_kernel<4><<<dim3(8, 32), 512, 0, stream>>>(
      h1, 2048, ff2_t, 2048, 2048, out, 2048, ff2_b, x);
  ln_kernel<<<M_ROWS, 256, 0, stream>>>(out, gamma, beta);
}